// Round 3
// baseline (357.315 us; speedup 1.0000x reference)
//
#include <hip/hip_runtime.h>
#include <hip/hip_bf16.h>

// MultiHeadAttention: B=4, N=2048, D=1024, H=16, HD=64, causal.
// Contract: f32 inputs AND f32 output; bf16 internal compute.
// R12 = R11 with fixed host-pass compile guard on the K=16 MFMA helper.
// R11: P-in-registers flash attention.
//  - Swapped QK^T lane layout P[q=l16][kv=16ni+quad*4+r] IS the A-fragment
//    of v_mfma_f32_16x16x16_bf16 (m=l16, k=quad*4+j). P never touches LDS:
//    exp2+cvt feeds the K=16 PV MFMA directly. Ps buffer deleted.
//  - LDS 70656 -> 35840 B -> 4 blocks/CU; grid (64 bh, 16 qi) = 1024 blocks
//    = exact full residency (32 waves/CU). qi permuted so each CU's 4
//    resident blocks sum to equal work; long blocks dispatch first.
//  - l_sum via K=16 MFMA vs ones-fragment (same C layout as before).

#define BB 4
#define NN 2048
#define DD 1024
#define HH 16
#define HD 64
#define MM (BB * NN) // 8192

typedef __bf16 bf16;
typedef __bf16 bf16x4 __attribute__((ext_vector_type(4)));
typedef __bf16 bf16x8 __attribute__((ext_vector_type(8)));
typedef float f32x4 __attribute__((ext_vector_type(4)));
typedef short short4v __attribute__((ext_vector_type(4)));

// K=16 bf16 MFMA (A,B = 4 bf16 / 2 VGPR per lane). Host pass must not see
// any amdgcn builtin identifier (it parses both sides of __has_builtin).
__device__ __forceinline__ f32x4 mfma16x16x16(short4v a, short4v b, f32x4 c) {
#if defined(__HIP_DEVICE_COMPILE__)
#if __has_builtin(__builtin_amdgcn_mfma_f32_16x16x16bf16_1k)
    return __builtin_amdgcn_mfma_f32_16x16x16bf16_1k(a, b, c, 0, 0, 0);
#else
    f32x4 d;
    asm("v_mfma_f32_16x16x16_bf16 %0, %1, %2, %3"
        : "=&v"(d)
        : "v"(a), "v"(b), "v"(c));
    return d;
#endif
#else
    (void)a; (void)b;
    return c;
#endif
}

// Async 16B global->LDS copy. LDS dest must follow wave-uniform base + lane*16.
__device__ __forceinline__ void async_copy16(bf16* lds, const bf16* g) {
    __builtin_amdgcn_global_load_lds(
        (const __attribute__((address_space(1))) void*)g,
        (__attribute__((address_space(3))) void*)lds, 16, 0, 0);
}

// ---------------------------------------------------------------------------
// x: f32 [B*N*D] -> bf16
// ---------------------------------------------------------------------------
__global__ void convert_x(const float* __restrict__ x, bf16* __restrict__ xb) {
    int i = (blockIdx.x * 256 + threadIdx.x) * 4;
    float4 v = *(const float4*)&x[i];
    xb[i + 0] = (bf16)v.x;
    xb[i + 1] = (bf16)v.y;
    xb[i + 2] = (bf16)v.z;
    xb[i + 3] = (bf16)v.w;
}

// ---------------------------------------------------------------------------
// Weight transpose + convert (all 4 weights in one launch, z selects):
// Wt[z][n][k] = (bf16)W_z[k][n]  (D x D)
// ---------------------------------------------------------------------------
__global__ void transpose_w4(const float* __restrict__ W0, const float* __restrict__ W1,
                             const float* __restrict__ W2, const float* __restrict__ W3,
                             bf16* __restrict__ Wt) {
    __shared__ float tile[32][33];
    const float* W = (blockIdx.z == 0) ? W0 : (blockIdx.z == 1) ? W1
                    : (blockIdx.z == 2) ? W2 : W3;
    bf16* out = Wt + (size_t)blockIdx.z * DD * DD;
    int tx = threadIdx.x, ty = threadIdx.y;
    int x0 = blockIdx.x * 32, y0 = blockIdx.y * 32;
#pragma unroll
    for (int i = 0; i < 32; i += 8)
        tile[ty + i][tx] = W[(size_t)(y0 + ty + i) * DD + x0 + tx];
    __syncthreads();
#pragma unroll
    for (int i = 0; i < 32; i += 8)
        out[(size_t)(x0 + ty + i) * DD + y0 + tx] = (bf16)tile[tx][ty + i];
}

// ---------------------------------------------------------------------------
// GEMM: C[M,N] = A[M,K] * W[K,N] + bias, via Wt[N,K] (B^T form), bf16 MFMA.
// 128x128 block tile, 4 waves in 2x2, each wave 64x64 (4x4 MFMA 16x16x32).
// MODE 0: QKV fused (z==0 Q: scaled by 0.125*log2e for exp2 softmax).
//         z==0/1 (Q,K): bf16 out [B*H, N, HD]; z==2 (V): bf16 out [B*H, HD, N].
//         Epilogue staged through LDS for fully-coalesced global stores.
// MODE 1: out-projection, f32 output, plain [M, N].
// ---------------------------------------------------------------------------
template <int MODE>
__global__ __launch_bounds__(256) void gemm_bt(
    const bf16* __restrict__ A, const bf16* __restrict__ Wt,
    const float* __restrict__ b0, const float* __restrict__ b1,
    const float* __restrict__ b2, void* __restrict__ out0,
    void* __restrict__ out1, void* __restrict__ out2) {
    const int K = DD;
    __shared__ __align__(16) bf16 As[128 * 32];
    __shared__ __align__(16) bf16 Bs[128 * 32];
    __shared__ __align__(16) bf16 Cs[MODE == 0 ? 128 * 136 : 1]; // epilogue stage

    int m0 = blockIdx.x * 128;
    int n0 = blockIdx.y * 128;

    const bf16* Wz;
    const float* bias;
    void* out;
    float scale = 1.0f;
    int z = 0;
    if (MODE == 0) {
        z = blockIdx.z;
        Wz = Wt + (size_t)z * DD * DD;
        bias = (z == 0) ? b0 : ((z == 1) ? b1 : b2);
        out = (z == 0) ? out0 : ((z == 1) ? out1 : out2);
        if (z == 0) scale = 0.125f * 1.44269504f; // (1/sqrt(HD)) * log2(e)
    } else {
        Wz = Wt; bias = b0; out = out0;
    }

    int tid = threadIdx.x;
    int w = tid >> 6, lane = tid & 63;
    int wm = w >> 1, wn = w & 1;
    int quad = lane >> 4, l16 = lane & 15;

    f32x4 acc[4][4];
#pragma unroll
    for (int i = 0; i < 4; i++)
#pragma unroll
        for (int j = 0; j < 4; j++) acc[i][j] = (f32x4){0.f, 0.f, 0.f, 0.f};

    for (int k0 = 0; k0 < K; k0 += 32) {
        __syncthreads(); // previous iteration's LDS reads complete
#pragma unroll
        for (int j = 0; j < 2; j++) {
            int c = j * 256 + w * 64 + lane; // lds dest contiguous per wave
            int row = c >> 2, kk = (c & 3) * 8;
            async_copy16(&As[c * 8], &A[(size_t)(m0 + row) * K + k0 + kk]);
            async_copy16(&Bs[c * 8], &Wz[(size_t)(n0 + row) * K + k0 + kk]);
        }
        __syncthreads(); // drains vmcnt(0) before barrier

        bf16x8 af[4], bfm[4];
#pragma unroll
        for (int i = 0; i < 4; i++) {
            af[i] = *(const bf16x8*)&As[(wm * 64 + i * 16 + l16) * 32 + quad * 8];
            bfm[i] = *(const bf16x8*)&Bs[(wn * 64 + i * 16 + l16) * 32 + quad * 8];
        }
#pragma unroll
        for (int i = 0; i < 4; i++)
#pragma unroll
            for (int j = 0; j < 4; j++)
                acc[i][j] = __builtin_amdgcn_mfma_f32_16x16x32_bf16(
                    af[i], bfm[j], acc[i][j], 0, 0, 0);
    }

    // Epilogue. C/D layout: col = lane&15, row = quad*4 + reg.
    if (MODE == 0) {
        // Stage bias-applied bf16 C-tile into LDS.
        // z<2: Cs[m_local*136 + n_local];  z==2: transposed Cs[n_local*136 + m_local]
#pragma unroll
        for (int j = 0; j < 4; j++) {
            int nl = wn * 64 + j * 16 + l16;
            float bv = bias[n0 + nl];
#pragma unroll
            for (int i = 0; i < 4; i++) {
#pragma unroll
                for (int r = 0; r < 4; r++) {
                    int ml = wm * 64 + i * 16 + quad * 4 + r;
                    bf16 v = (bf16)((acc[i][j][r] + bv) * scale);
                    if (z == 2) Cs[nl * 136 + ml] = v;
                    else        Cs[ml * 136 + nl] = v;
                }
            }
        }
        __syncthreads();

        int bidx = m0 >> 11;          // batch (tile never crosses batch)
        int tok0 = m0 & (NN - 1);
        int hh0 = n0 >> 6;            // first of the 2 heads this tile covers
        if (z != 2) {
            // out [bh][tok][hd]: per head, (tok,hd) is one contiguous 16KB run.
#pragma unroll
            for (int hf = 0; hf < 2; hf++) {
                bf16* base = (bf16*)out + ((size_t)(bidx * HH + hh0 + hf) * NN + tok0) * HD;
#pragma unroll
                for (int k = 0; k < 4; k++) {
                    int f = k * 2048 + tid * 8;       // 0..8191, tok=f>>6, hd=f&63
                    int tok = f >> 6, hd = f & 63;
                    *(bf16x8*)&base[f] = *(const bf16x8*)&Cs[tok * 136 + hf * 64 + hd];
                }
            }
        } else {
            // V^T out [bh][hd][tok]: per (head,hd), tok-row is contiguous 256B.
#pragma unroll
            for (int hf = 0; hf < 2; hf++) {
#pragma unroll
                for (int k = 0; k < 4; k++) {
                    int hd = k * 16 + (tid >> 4);     // 0..63
                    int tk = (tid & 15) * 8;
                    bf16* dst = (bf16*)out +
                        ((size_t)(bidx * HH + hh0 + hf) * HD + hd) * NN + tok0 + tk;
                    *(bf16x8*)dst = *(const bf16x8*)&Cs[(hf * 64 + hd) * 136 + tk];
                }
            }
        }
    } else {
#pragma unroll
        for (int j = 0; j < 4; j++) {
            int n = n0 + wn * 64 + j * 16 + l16;
            float bv = bias[n];
#pragma unroll
            for (int i = 0; i < 4; i++) {
                int mrow = m0 + wm * 64 + i * 16 + quad * 4;
#pragma unroll
                for (int r = 0; r < 4; r++)
                    ((float*)out)[(size_t)(mrow + r) * DD + n] = acc[i][j][r] + bv;
            }
        }
    }
}

// ---------------------------------------------------------------------------
// Flash attention (causal, no-max softmax) — R12: P-in-registers.
// grid = (B*H, 16), block = 512 threads (8 waves x 16 q-rows = 128-row q-tile).
// Each block does ONE q-tile; qi permuted per blockIdx.y so the 4 blocks a CU
// hosts sum to equal work (30 tile-iters) and long blocks dispatch first.
// Swapped QK^T: s = mfma(K,Q) -> lane holds P[q=l16][kv=16ni+quad*4+r], which
// is exactly the A-frag of mfma_f32_16x16x16_bf16 (m=l16, k=quad*4+j).
// P goes straight from registers into the K=16 PV MFMA; no P LDS buffer.
// Per tile: barrier -> ds_write(prefetched regs) -> barrier -> issue loads
// for t+1 -> compute t (load latency hidden behind compute).
// ---------------------------------------------------------------------------
__global__ __launch_bounds__(512, 8) void flash_attn(
    const bf16* __restrict__ Q, const bf16* __restrict__ Kg,
    const bf16* __restrict__ Vt_g, bf16* __restrict__ Oc) {
    __shared__ __align__(16) bf16 Ks[128 * 72];   // [kv][hd], stride 72
    __shared__ __align__(16) bf16 Vs[64 * 136];   // [d][kv], stride 136

    int bh = blockIdx.x;              // linear id % 8 == bh % 8 -> XCD locality
    int b = bh >> 4, h = bh & 15;
    int tid = threadIdx.x;
    int w = tid >> 6, lane = tid & 63;
    int quad = lane >> 4, l16 = lane & 15;

    // Balanced qi permutation: y = ya + 4*yb; CU hosting {yb=0..3} at fixed ya
    // gets qi summing to 30. yb=0 (dispatched first) gets the longest tiles.
    int y = blockIdx.y;
    int ya = y & 3, bp = 3 - (y >> 2);
    int qi = (bp < 2) ? (4 * bp + ya) : (4 * bp + 3 - ya);
    int q0 = qi * 128;

    const bf16* Qb = Q + (size_t)bh * NN * HD;
    const bf16* Kb = Kg + (size_t)bh * NN * HD;
    const bf16* Vtb = Vt_g + (size_t)bh * HD * NN;

    const short4v ones16 = {0x3F80, 0x3F80, 0x3F80, 0x3F80}; // bf16 1.0 x4

    // Per-thread staging coordinates (fixed across tiles). 512 threads stage
    // a 128x64 K-tile and a 64x128 V^T-tile with 2 b128 chunks each.
    int kr[2], kc[2], vd[2], vk[2];
#pragma unroll
    for (int j = 0; j < 2; j++) {
        int c = j * 512 + tid;
        kr[j] = c >> 3; kc[j] = (c & 7) * 8;   // K: row, col-chunk
        vd[j] = c >> 4; vk[j] = (c & 15) * 8;  // V^T: d, kv-chunk
    }

    int qrow = q0 + w * 16 + l16;              // this lane's q (qf col & mask)

    // This wave's Q fragments (B-operand for swapped mfma: col=l16=q,
    // k = ks*32 + quad*8 + j over HD).
    bf16x8 qf[2];
#pragma unroll
    for (int ks = 0; ks < 2; ks++)
        qf[ks] = *(const bf16x8*)&Qb[(size_t)qrow * HD + ks * 32 + quad * 8];

    f32x4 l_sum = (f32x4){0.f, 0.f, 0.f, 0.f};
    f32x4 o_acc[4];
#pragma unroll
    for (int di = 0; di < 4; di++) o_acc[di] = (f32x4){0.f, 0.f, 0.f, 0.f};

    // Preload tile 0 into registers.
    bf16x8 kreg[2], vreg[2];
#pragma unroll
    for (int j = 0; j < 2; j++) {
        kreg[j] = *(const bf16x8*)&Kb[(size_t)kr[j] * HD + kc[j]];
        vreg[j] = *(const bf16x8*)&Vtb[(size_t)vd[j] * NN + vk[j]];
    }

    for (int t = 0; t <= qi; t++) {
        __syncthreads(); // previous iteration's LDS reads complete
        // Commit prefetched tile t to LDS.
#pragma unroll
        for (int j = 0; j < 2; j++) {
            *(bf16x8*)&Ks[kr[j] * 72 + kc[j]] = kreg[j];
            *(bf16x8*)&Vs[vd[j] * 136 + vk[j]] = vreg[j];
        }
        __syncthreads();

        // Issue loads for tile t+1 (latency overlaps compute below).
        if (t < qi) {
            int kvn = (t + 1) * 128;
#pragma unroll
            for (int j = 0; j < 2; j++) {
                kreg[j] = *(const bf16x8*)&Kb[(size_t)(kvn + kr[j]) * HD + kc[j]];
                vreg[j] = *(const bf16x8*)&Vtb[(size_t)vd[j] * NN + kvn + vk[j]];
            }
        }

        int kv0 = t * 128;
        bool diag = (t == qi);
        // S^T = K * Q^T per 16-kv band. C-layout: row=kv=quad*4+r, col=q=l16.
#pragma unroll
        for (int ni = 0; ni < 8; ni++) {
            bf16x8 bk0 = *(const bf16x8*)&Ks[(ni * 16 + l16) * 72 + quad * 8];
            bf16x8 bk1 = *(const bf16x8*)&Ks[(ni * 16 + l16) * 72 + 32 + quad * 8];
            f32x4 s = (f32x4){0.f, 0.f, 0.f, 0.f};
            s = __builtin_amdgcn_mfma_f32_16x16x32_bf16(bk0, qf[0], s, 0, 0, 0);
            s = __builtin_amdgcn_mfma_f32_16x16x32_bf16(bk1, qf[1], s, 0, 0, 0);
            // lane holds S[qrow][kv0 + ni*16 + quad*4 + r], r=0..3 == the
            // A-fragment rows of the K=16 PV mfma. Exp + cvt, stay in regs.
            bf16x4 pb;
            if (diag) {
                int kvb = kv0 + ni * 16 + quad * 4;
#pragma unroll
                for (int r = 0; r < 4; r++)
                    pb[r] = (bf16)((kvb + r > qrow) ? 0.f : exp2f(s[r]));
            } else {
#pragma unroll
                for (int r = 0; r < 4; r++) pb[r] = (bf16)exp2f(s[r]);
            }
            short4v pv = __builtin_bit_cast(short4v, pb);
            // Row-sum via K=16 MFMA against ones (C row=quad*4+r matches o_acc).
            l_sum = mfma16x16x16(pv, ones16, l_sum);
            // PV: B-frag = V[kv=quad*4+j][d=di*16+l16] from V^T rows (b64 reads).
#pragma unroll
            for (int di = 0; di < 4; di++) {
                short4v vb = *(const short4v*)&Vs[(di * 16 + l16) * 136 + ni * 16 + quad * 4];
                o_acc[di] = mfma16x16x16(pv, vb, o_acc[di]);
            }
        }
    }

    // Epilogue: O/l -> [B, N, H*HD] (concat-head layout for the O-proj GEMM)
    // C-layout: row = q = quad*4 + r (within wave's 16), col = d = l16.
#pragma unroll
    for (int r = 0; r < 4; r++) {
        float inv = 1.0f / l_sum[r];
        int tok = q0 + w * 16 + quad * 4 + r;
#pragma unroll
        for (int di = 0; di < 4; di++) {
            int d = h * 64 + di * 16 + l16;
            Oc[((size_t)(b * NN + tok)) * DD + d] = (bf16)(o_acc[di][r] * inv);
        }
    }
}

// ---------------------------------------------------------------------------
extern "C" void kernel_launch(void* const* d_in, const int* in_sizes, int n_in,
                              void* d_out, int out_size, void* d_ws, size_t ws_size,
                              hipStream_t stream) {
    const float* x  = (const float*)d_in[0];
    const float* Wq = (const float*)d_in[1];
    const float* bq = (const float*)d_in[2];
    const float* Wk = (const float*)d_in[3];
    const float* bk = (const float*)d_in[4];
    const float* Wv = (const float*)d_in[5];
    const float* bv = (const float*)d_in[6];
    const float* Wo = (const float*)d_in[7];
    const float* bo = (const float*)d_in[8];

    const size_t need = (size_t)(8388608ull * 5 + 4194304ull) * sizeof(bf16);
    if (ws_size < need) return; // diagnostic: leaves d_out zeroed (absmax 3.8125)

    bf16* ws = (bf16*)d_ws;
    bf16* xb = ws;
    bf16* wt = xb + (size_t)MM * DD;
    bf16* Qw = wt + 4ull * DD * DD;       // [B*H, N, HD], pre-scaled 0.125*log2e
    bf16* Kw = Qw + (size_t)MM * DD;      // [B*H, N, HD]
    bf16* Vw = Kw + (size_t)MM * DD;      // V^T [B*H, HD, N]
    bf16* Aw = Vw + (size_t)MM * DD;      // attention out [B, N, D]

    convert_x<<<dim3(MM * DD / 1024), 256, 0, stream>>>(x, xb);

    transpose_w4<<<dim3(32, 32, 4), dim3(32, 8), 0, stream>>>(Wq, Wk, Wv, Wo, wt);

    gemm_bt<0><<<dim3(MM / 128, DD / 128, 3), 256, 0, stream>>>(
        xb, wt, bq, bk, bv, Qw, Kw, Vw);

    // grid (bh, qi-perm): linear id % 8 == bh % 8 -> one XCD per head group;
    // 1024 blocks x 35840B LDS = 4 blocks/CU = full residency.
    flash_attn<<<dim3(BB * HH, 16), 512, 0, stream>>>(Qw, Kw, Vw, Aw);

    gemm_bt<1><<<dim3(MM / 128, DD / 128, 1), 256, 0, stream>>>(
        Aw, wt + 3ull * DD * DD, bo, bo, bo, d_out, d_out, d_out);
}

// Round 4
// 276.672 us; speedup vs baseline: 1.2915x; 1.2915x over previous
//
#include <hip/hip_runtime.h>
#include <hip/hip_bf16.h>

// MultiHeadAttention: B=4, N=2048, D=1024, H=16, HD=64, causal.
// Contract: f32 inputs AND f32 output; bf16 internal compute.
// R13 = R12's P-in-registers compute (verified correct) + R10's grid/launch
// shape. R12's launch_bounds(512,8) forced a 64-VGPR cap -> spill storm
// (WRITE_SIZE 363MB of scratch). R13 uses (512,4): no spill, 2 blocks/CU.
//  - Swapped QK^T lane layout P[q=l16][kv=16ni+quad*4+r] IS the A-fragment
//    of v_mfma_f32_16x16x16_bf16 (m=l16, k=quad*4+j). P never touches LDS.
//  - LDS 35840 B (Ks+Vs only; Ps deleted).
//  - grid (8, B*H) paired q-tiles qi / 15-qi: 512 blocks, every block
//    exactly 17 tile-iters, one balanced pass at 2 blocks/CU.

#define BB 4
#define NN 2048
#define DD 1024
#define HH 16
#define HD 64
#define MM (BB * NN) // 8192

typedef __bf16 bf16;
typedef __bf16 bf16x4 __attribute__((ext_vector_type(4)));
typedef __bf16 bf16x8 __attribute__((ext_vector_type(8)));
typedef float f32x4 __attribute__((ext_vector_type(4)));
typedef short short4v __attribute__((ext_vector_type(4)));

// K=16 bf16 MFMA (A,B = 4 bf16 / 2 VGPR per lane). Host pass must not see
// any amdgcn builtin identifier (it parses both sides of __has_builtin).
__device__ __forceinline__ f32x4 mfma16x16x16(short4v a, short4v b, f32x4 c) {
#if defined(__HIP_DEVICE_COMPILE__)
#if __has_builtin(__builtin_amdgcn_mfma_f32_16x16x16bf16_1k)
    return __builtin_amdgcn_mfma_f32_16x16x16bf16_1k(a, b, c, 0, 0, 0);
#else
    f32x4 d;
    asm("v_mfma_f32_16x16x16_bf16 %0, %1, %2, %3"
        : "=&v"(d)
        : "v"(a), "v"(b), "v"(c));
    return d;
#endif
#else
    (void)a; (void)b;
    return c;
#endif
}

// Async 16B global->LDS copy. LDS dest must follow wave-uniform base + lane*16.
__device__ __forceinline__ void async_copy16(bf16* lds, const bf16* g) {
    __builtin_amdgcn_global_load_lds(
        (const __attribute__((address_space(1))) void*)g,
        (__attribute__((address_space(3))) void*)lds, 16, 0, 0);
}

// ---------------------------------------------------------------------------
// x: f32 [B*N*D] -> bf16
// ---------------------------------------------------------------------------
__global__ void convert_x(const float* __restrict__ x, bf16* __restrict__ xb) {
    int i = (blockIdx.x * 256 + threadIdx.x) * 4;
    float4 v = *(const float4*)&x[i];
    xb[i + 0] = (bf16)v.x;
    xb[i + 1] = (bf16)v.y;
    xb[i + 2] = (bf16)v.z;
    xb[i + 3] = (bf16)v.w;
}

// ---------------------------------------------------------------------------
// Weight transpose + convert (all 4 weights in one launch, z selects):
// Wt[z][n][k] = (bf16)W_z[k][n]  (D x D)
// ---------------------------------------------------------------------------
__global__ void transpose_w4(const float* __restrict__ W0, const float* __restrict__ W1,
                             const float* __restrict__ W2, const float* __restrict__ W3,
                             bf16* __restrict__ Wt) {
    __shared__ float tile[32][33];
    const float* W = (blockIdx.z == 0) ? W0 : (blockIdx.z == 1) ? W1
                    : (blockIdx.z == 2) ? W2 : W3;
    bf16* out = Wt + (size_t)blockIdx.z * DD * DD;
    int tx = threadIdx.x, ty = threadIdx.y;
    int x0 = blockIdx.x * 32, y0 = blockIdx.y * 32;
#pragma unroll
    for (int i = 0; i < 32; i += 8)
        tile[ty + i][tx] = W[(size_t)(y0 + ty + i) * DD + x0 + tx];
    __syncthreads();
#pragma unroll
    for (int i = 0; i < 32; i += 8)
        out[(size_t)(x0 + ty + i) * DD + y0 + tx] = (bf16)tile[tx][ty + i];
}

// ---------------------------------------------------------------------------
// GEMM: C[M,N] = A[M,K] * W[K,N] + bias, via Wt[N,K] (B^T form), bf16 MFMA.
// 128x128 block tile, 4 waves in 2x2, each wave 64x64 (4x4 MFMA 16x16x32).
// MODE 0: QKV fused (z==0 Q: scaled by 0.125*log2e for exp2 softmax).
//         z==0/1 (Q,K): bf16 out [B*H, N, HD]; z==2 (V): bf16 out [B*H, HD, N].
//         Epilogue staged through LDS for fully-coalesced global stores.
// MODE 1: out-projection, f32 output, plain [M, N].
// ---------------------------------------------------------------------------
template <int MODE>
__global__ __launch_bounds__(256) void gemm_bt(
    const bf16* __restrict__ A, const bf16* __restrict__ Wt,
    const float* __restrict__ b0, const float* __restrict__ b1,
    const float* __restrict__ b2, void* __restrict__ out0,
    void* __restrict__ out1, void* __restrict__ out2) {
    const int K = DD;
    __shared__ __align__(16) bf16 As[128 * 32];
    __shared__ __align__(16) bf16 Bs[128 * 32];
    __shared__ __align__(16) bf16 Cs[MODE == 0 ? 128 * 136 : 1]; // epilogue stage

    int m0 = blockIdx.x * 128;
    int n0 = blockIdx.y * 128;

    const bf16* Wz;
    const float* bias;
    void* out;
    float scale = 1.0f;
    int z = 0;
    if (MODE == 0) {
        z = blockIdx.z;
        Wz = Wt + (size_t)z * DD * DD;
        bias = (z == 0) ? b0 : ((z == 1) ? b1 : b2);
        out = (z == 0) ? out0 : ((z == 1) ? out1 : out2);
        if (z == 0) scale = 0.125f * 1.44269504f; // (1/sqrt(HD)) * log2(e)
    } else {
        Wz = Wt; bias = b0; out = out0;
    }

    int tid = threadIdx.x;
    int w = tid >> 6, lane = tid & 63;
    int wm = w >> 1, wn = w & 1;
    int quad = lane >> 4, l16 = lane & 15;

    f32x4 acc[4][4];
#pragma unroll
    for (int i = 0; i < 4; i++)
#pragma unroll
        for (int j = 0; j < 4; j++) acc[i][j] = (f32x4){0.f, 0.f, 0.f, 0.f};

    for (int k0 = 0; k0 < K; k0 += 32) {
        __syncthreads(); // previous iteration's LDS reads complete
#pragma unroll
        for (int j = 0; j < 2; j++) {
            int c = j * 256 + w * 64 + lane; // lds dest contiguous per wave
            int row = c >> 2, kk = (c & 3) * 8;
            async_copy16(&As[c * 8], &A[(size_t)(m0 + row) * K + k0 + kk]);
            async_copy16(&Bs[c * 8], &Wz[(size_t)(n0 + row) * K + k0 + kk]);
        }
        __syncthreads(); // drains vmcnt(0) before barrier

        bf16x8 af[4], bfm[4];
#pragma unroll
        for (int i = 0; i < 4; i++) {
            af[i] = *(const bf16x8*)&As[(wm * 64 + i * 16 + l16) * 32 + quad * 8];
            bfm[i] = *(const bf16x8*)&Bs[(wn * 64 + i * 16 + l16) * 32 + quad * 8];
        }
#pragma unroll
        for (int i = 0; i < 4; i++)
#pragma unroll
            for (int j = 0; j < 4; j++)
                acc[i][j] = __builtin_amdgcn_mfma_f32_16x16x32_bf16(
                    af[i], bfm[j], acc[i][j], 0, 0, 0);
    }

    // Epilogue. C/D layout: col = lane&15, row = quad*4 + reg.
    if (MODE == 0) {
        // Stage bias-applied bf16 C-tile into LDS.
        // z<2: Cs[m_local*136 + n_local];  z==2: transposed Cs[n_local*136 + m_local]
#pragma unroll
        for (int j = 0; j < 4; j++) {
            int nl = wn * 64 + j * 16 + l16;
            float bv = bias[n0 + nl];
#pragma unroll
            for (int i = 0; i < 4; i++) {
#pragma unroll
                for (int r = 0; r < 4; r++) {
                    int ml = wm * 64 + i * 16 + quad * 4 + r;
                    bf16 v = (bf16)((acc[i][j][r] + bv) * scale);
                    if (z == 2) Cs[nl * 136 + ml] = v;
                    else        Cs[ml * 136 + nl] = v;
                }
            }
        }
        __syncthreads();

        int bidx = m0 >> 11;          // batch (tile never crosses batch)
        int tok0 = m0 & (NN - 1);
        int hh0 = n0 >> 6;            // first of the 2 heads this tile covers
        if (z != 2) {
            // out [bh][tok][hd]: per head, (tok,hd) is one contiguous 16KB run.
#pragma unroll
            for (int hf = 0; hf < 2; hf++) {
                bf16* base = (bf16*)out + ((size_t)(bidx * HH + hh0 + hf) * NN + tok0) * HD;
#pragma unroll
                for (int k = 0; k < 4; k++) {
                    int f = k * 2048 + tid * 8;       // 0..8191, tok=f>>6, hd=f&63
                    int tok = f >> 6, hd = f & 63;
                    *(bf16x8*)&base[f] = *(const bf16x8*)&Cs[tok * 136 + hf * 64 + hd];
                }
            }
        } else {
            // V^T out [bh][hd][tok]: per (head,hd), tok-row is contiguous 256B.
#pragma unroll
            for (int hf = 0; hf < 2; hf++) {
#pragma unroll
                for (int k = 0; k < 4; k++) {
                    int hd = k * 16 + (tid >> 4);     // 0..63
                    int tk = (tid & 15) * 8;
                    bf16* dst = (bf16*)out +
                        ((size_t)(bidx * HH + hh0 + hf) * HD + hd) * NN + tok0 + tk;
                    *(bf16x8*)dst = *(const bf16x8*)&Cs[(hf * 64 + hd) * 136 + tk];
                }
            }
        }
    } else {
#pragma unroll
        for (int j = 0; j < 4; j++) {
            int n = n0 + wn * 64 + j * 16 + l16;
            float bv = bias[n];
#pragma unroll
            for (int i = 0; i < 4; i++) {
                int mrow = m0 + wm * 64 + i * 16 + quad * 4;
#pragma unroll
                for (int r = 0; r < 4; r++)
                    ((float*)out)[(size_t)(mrow + r) * DD + n] = acc[i][j][r] + bv;
            }
        }
    }
}

// ---------------------------------------------------------------------------
// Flash attention (causal, no-max softmax) — R13: P-in-registers, no spill.
// grid = (8, B*H), block = 512 threads (8 waves x 16 q-rows = 128-row q-tile).
// Block does q-tiles qi=blockIdx.x and 15-blockIdx.x sequentially: every
// block is exactly 17 tile-iters; 512 blocks = one balanced pass, 2/CU.
// Swapped QK^T: s = mfma(K,Q) -> lane holds P[q=l16][kv=16ni+quad*4+r], which
// is exactly the A-frag of mfma_f32_16x16x16_bf16 (m=l16, k=quad*4+j).
// P goes straight from registers into the K=16 PV MFMA; no P LDS buffer.
// Per tile: barrier -> ds_write(prefetched regs) -> barrier -> issue loads
// for t+1 -> compute t (load latency hidden behind compute).
// ---------------------------------------------------------------------------
__global__ __launch_bounds__(512, 4) void flash_attn(
    const bf16* __restrict__ Q, const bf16* __restrict__ Kg,
    const bf16* __restrict__ Vt_g, bf16* __restrict__ Oc) {
    __shared__ __align__(16) bf16 Ks[128 * 72];   // [kv][hd], stride 72
    __shared__ __align__(16) bf16 Vs[64 * 136];   // [d][kv], stride 136

    int bh = blockIdx.y;
    int b = bh >> 4, h = bh & 15;
    int tid = threadIdx.x;
    int w = tid >> 6, lane = tid & 63;
    int quad = lane >> 4, l16 = lane & 15;

    const bf16* Qb = Q + (size_t)bh * NN * HD;
    const bf16* Kb = Kg + (size_t)bh * NN * HD;
    const bf16* Vtb = Vt_g + (size_t)bh * HD * NN;

    const short4v ones16 = {0x3F80, 0x3F80, 0x3F80, 0x3F80}; // bf16 1.0 x4

    // Per-thread staging coordinates (fixed across tiles). 512 threads stage
    // a 128x64 K-tile and a 64x128 V^T-tile with 2 b128 chunks each.
    int kr[2], kc[2], vd[2], vk[2];
#pragma unroll
    for (int j = 0; j < 2; j++) {
        int c = j * 512 + tid;
        kr[j] = c >> 3; kc[j] = (c & 7) * 8;   // K: row, col-chunk
        vd[j] = c >> 4; vk[j] = (c & 15) * 8;  // V^T: d, kv-chunk
    }

    for (int phase = 0; phase < 2; phase++) {
        int qi = (phase == 0) ? blockIdx.x : (15 - blockIdx.x);
        int q0 = qi * 128;
        int qrow = q0 + w * 16 + l16;          // this lane's q (qf col & mask)

        // This wave's Q fragments (B-operand for swapped mfma: col=l16=q,
        // k = ks*32 + quad*8 + j over HD).
        bf16x8 qf[2];
#pragma unroll
        for (int ks = 0; ks < 2; ks++)
            qf[ks] = *(const bf16x8*)&Qb[(size_t)qrow * HD + ks * 32 + quad * 8];

        f32x4 l_sum = (f32x4){0.f, 0.f, 0.f, 0.f};
        f32x4 o_acc[4];
#pragma unroll
        for (int di = 0; di < 4; di++) o_acc[di] = (f32x4){0.f, 0.f, 0.f, 0.f};

        // Preload tile 0 into registers.
        bf16x8 kreg[2], vreg[2];
#pragma unroll
        for (int j = 0; j < 2; j++) {
            kreg[j] = *(const bf16x8*)&Kb[(size_t)kr[j] * HD + kc[j]];
            vreg[j] = *(const bf16x8*)&Vtb[(size_t)vd[j] * NN + vk[j]];
        }

        for (int t = 0; t <= qi; t++) {
            __syncthreads(); // previous iteration's LDS reads complete
            // Commit prefetched tile t to LDS.
#pragma unroll
            for (int j = 0; j < 2; j++) {
                *(bf16x8*)&Ks[kr[j] * 72 + kc[j]] = kreg[j];
                *(bf16x8*)&Vs[vd[j] * 136 + vk[j]] = vreg[j];
            }
            __syncthreads();

            // Issue loads for tile t+1 (latency overlaps compute below).
            if (t < qi) {
                int kvn = (t + 1) * 128;
#pragma unroll
                for (int j = 0; j < 2; j++) {
                    kreg[j] = *(const bf16x8*)&Kb[(size_t)(kvn + kr[j]) * HD + kc[j]];
                    vreg[j] = *(const bf16x8*)&Vtb[(size_t)vd[j] * NN + kvn + vk[j]];
                }
            }

            int kv0 = t * 128;
            bool diag = (t == qi);
            // S^T = K * Q^T per 16-kv band. C-layout: row=kv=quad*4+r, col=q=l16.
#pragma unroll
            for (int ni = 0; ni < 8; ni++) {
                bf16x8 bk0 = *(const bf16x8*)&Ks[(ni * 16 + l16) * 72 + quad * 8];
                bf16x8 bk1 = *(const bf16x8*)&Ks[(ni * 16 + l16) * 72 + 32 + quad * 8];
                f32x4 s = (f32x4){0.f, 0.f, 0.f, 0.f};
                s = __builtin_amdgcn_mfma_f32_16x16x32_bf16(bk0, qf[0], s, 0, 0, 0);
                s = __builtin_amdgcn_mfma_f32_16x16x32_bf16(bk1, qf[1], s, 0, 0, 0);
                // lane holds S[qrow][kv0 + ni*16 + quad*4 + r], r=0..3 == the
                // A-fragment rows of the K=16 PV mfma. Exp + cvt, stay in regs.
                bf16x4 pb;
                if (diag) {
                    int kvb = kv0 + ni * 16 + quad * 4;
#pragma unroll
                    for (int r = 0; r < 4; r++)
                        pb[r] = (bf16)((kvb + r > qrow) ? 0.f : exp2f(s[r]));
                } else {
#pragma unroll
                    for (int r = 0; r < 4; r++) pb[r] = (bf16)exp2f(s[r]);
                }
                short4v pv = __builtin_bit_cast(short4v, pb);
                // Row-sum via K=16 MFMA against ones (C row=quad*4+r matches o_acc).
                l_sum = mfma16x16x16(pv, ones16, l_sum);
                // PV: B-frag = V[kv=quad*4+j][d=di*16+l16] from V^T rows (b64 reads).
#pragma unroll
                for (int di = 0; di < 4; di++) {
                    short4v vb = *(const short4v*)&Vs[(di * 16 + l16) * 136 + ni * 16 + quad * 4];
                    o_acc[di] = mfma16x16x16(pv, vb, o_acc[di]);
                }
            }
        }

        // Epilogue: O/l -> [B, N, H*HD] (concat-head layout for the O-proj GEMM)
        // C-layout: row = q = quad*4 + r (within wave's 16), col = d = l16.
#pragma unroll
        for (int r = 0; r < 4; r++) {
            float inv = 1.0f / l_sum[r];
            int tok = q0 + w * 16 + quad * 4 + r;
#pragma unroll
            for (int di = 0; di < 4; di++) {
                int d = h * 64 + di * 16 + l16;
                Oc[((size_t)(b * NN + tok)) * DD + d] = (bf16)(o_acc[di][r] * inv);
            }
        }
    }
}

// ---------------------------------------------------------------------------
extern "C" void kernel_launch(void* const* d_in, const int* in_sizes, int n_in,
                              void* d_out, int out_size, void* d_ws, size_t ws_size,
                              hipStream_t stream) {
    const float* x  = (const float*)d_in[0];
    const float* Wq = (const float*)d_in[1];
    const float* bq = (const float*)d_in[2];
    const float* Wk = (const float*)d_in[3];
    const float* bk = (const float*)d_in[4];
    const float* Wv = (const float*)d_in[5];
    const float* bv = (const float*)d_in[6];
    const float* Wo = (const float*)d_in[7];
    const float* bo = (const float*)d_in[8];

    const size_t need = (size_t)(8388608ull * 5 + 4194304ull) * sizeof(bf16);
    if (ws_size < need) return; // diagnostic: leaves d_out zeroed (absmax 3.8125)

    bf16* ws = (bf16*)d_ws;
    bf16* xb = ws;
    bf16* wt = xb + (size_t)MM * DD;
    bf16* Qw = wt + 4ull * DD * DD;       // [B*H, N, HD], pre-scaled 0.125*log2e
    bf16* Kw = Qw + (size_t)MM * DD;      // [B*H, N, HD]
    bf16* Vw = Kw + (size_t)MM * DD;      // V^T [B*H, HD, N]
    bf16* Aw = Vw + (size_t)MM * DD;      // attention out [B, N, D]

    convert_x<<<dim3(MM * DD / 1024), 256, 0, stream>>>(x, xb);

    transpose_w4<<<dim3(32, 32, 4), dim3(32, 8), 0, stream>>>(Wq, Wk, Wv, Wo, wt);

    gemm_bt<0><<<dim3(MM / 128, DD / 128, 3), 256, 0, stream>>>(
        xb, wt, bq, bk, bv, Qw, Kw, Vw);

    flash_attn<<<dim3(8, BB * HH), 512, 0, stream>>>(Qw, Kw, Vw, Aw);

    gemm_bt<1><<<dim3(MM / 128, DD / 128, 1), 256, 0, stream>>>(
        Aw, wt + 3ull * DD * DD, bo, bo, bo, d_out, d_out, d_out);
}

// Round 5
// 275.341 us; speedup vs baseline: 1.2977x; 1.0048x over previous
//
#include <hip/hip_runtime.h>
#include <hip/hip_bf16.h>

// MultiHeadAttention: B=4, N=2048, D=1024, H=16, HD=64, causal.
// Contract: f32 inputs AND f32 output; bf16 internal compute.
// R14 = R13 (P-in-registers, verified, VGPR=64 no spill) with the two fixes
// the R13 counters license:
//  - XCD affinity restored: grid (B*H, 16), bh on blockIdx.x -> linear id%8
//    = bh%8 (R13's q-oct-on-x scattered each head's K/V over all 8 XCDs:
//    FETCH 27->150MB regression).
//  - 4 blocks/CU: 1024 blocks x 35840B LDS x 64 VGPR -> 8 waves/SIMD.
//    One q-tile per block; R12's balanced qi permutation (each CU's 4
//    resident blocks sum to 34 tile-iters; long tiles dispatch first).
//    launch_bounds(512,4) is only a VGPR cap (128); no forced occupancy.

#define BB 4
#define NN 2048
#define DD 1024
#define HH 16
#define HD 64
#define MM (BB * NN) // 8192

typedef __bf16 bf16;
typedef __bf16 bf16x4 __attribute__((ext_vector_type(4)));
typedef __bf16 bf16x8 __attribute__((ext_vector_type(8)));
typedef float f32x4 __attribute__((ext_vector_type(4)));
typedef short short4v __attribute__((ext_vector_type(4)));

// K=16 bf16 MFMA (A,B = 4 bf16 / 2 VGPR per lane). Host pass must not see
// any amdgcn builtin identifier (it parses both sides of __has_builtin).
__device__ __forceinline__ f32x4 mfma16x16x16(short4v a, short4v b, f32x4 c) {
#if defined(__HIP_DEVICE_COMPILE__)
#if __has_builtin(__builtin_amdgcn_mfma_f32_16x16x16bf16_1k)
    return __builtin_amdgcn_mfma_f32_16x16x16bf16_1k(a, b, c, 0, 0, 0);
#else
    f32x4 d;
    asm("v_mfma_f32_16x16x16_bf16 %0, %1, %2, %3"
        : "=&v"(d)
        : "v"(a), "v"(b), "v"(c));
    return d;
#endif
#else
    (void)a; (void)b;
    return c;
#endif
}

// Async 16B global->LDS copy. LDS dest must follow wave-uniform base + lane*16.
__device__ __forceinline__ void async_copy16(bf16* lds, const bf16* g) {
    __builtin_amdgcn_global_load_lds(
        (const __attribute__((address_space(1))) void*)g,
        (__attribute__((address_space(3))) void*)lds, 16, 0, 0);
}

// ---------------------------------------------------------------------------
// x: f32 [B*N*D] -> bf16
// ---------------------------------------------------------------------------
__global__ void convert_x(const float* __restrict__ x, bf16* __restrict__ xb) {
    int i = (blockIdx.x * 256 + threadIdx.x) * 4;
    float4 v = *(const float4*)&x[i];
    xb[i + 0] = (bf16)v.x;
    xb[i + 1] = (bf16)v.y;
    xb[i + 2] = (bf16)v.z;
    xb[i + 3] = (bf16)v.w;
}

// ---------------------------------------------------------------------------
// Weight transpose + convert (all 4 weights in one launch, z selects):
// Wt[z][n][k] = (bf16)W_z[k][n]  (D x D)
// ---------------------------------------------------------------------------
__global__ void transpose_w4(const float* __restrict__ W0, const float* __restrict__ W1,
                             const float* __restrict__ W2, const float* __restrict__ W3,
                             bf16* __restrict__ Wt) {
    __shared__ float tile[32][33];
    const float* W = (blockIdx.z == 0) ? W0 : (blockIdx.z == 1) ? W1
                    : (blockIdx.z == 2) ? W2 : W3;
    bf16* out = Wt + (size_t)blockIdx.z * DD * DD;
    int tx = threadIdx.x, ty = threadIdx.y;
    int x0 = blockIdx.x * 32, y0 = blockIdx.y * 32;
#pragma unroll
    for (int i = 0; i < 32; i += 8)
        tile[ty + i][tx] = W[(size_t)(y0 + ty + i) * DD + x0 + tx];
    __syncthreads();
#pragma unroll
    for (int i = 0; i < 32; i += 8)
        out[(size_t)(x0 + ty + i) * DD + y0 + tx] = (bf16)tile[tx][ty + i];
}

// ---------------------------------------------------------------------------
// GEMM: C[M,N] = A[M,K] * W[K,N] + bias, via Wt[N,K] (B^T form), bf16 MFMA.
// 128x128 block tile, 4 waves in 2x2, each wave 64x64 (4x4 MFMA 16x16x32).
// MODE 0: QKV fused (z==0 Q: scaled by 0.125*log2e for exp2 softmax).
//         z==0/1 (Q,K): bf16 out [B*H, N, HD]; z==2 (V): bf16 out [B*H, HD, N].
//         Epilogue staged through LDS for fully-coalesced global stores.
// MODE 1: out-projection, f32 output, plain [M, N].
// ---------------------------------------------------------------------------
template <int MODE>
__global__ __launch_bounds__(256) void gemm_bt(
    const bf16* __restrict__ A, const bf16* __restrict__ Wt,
    const float* __restrict__ b0, const float* __restrict__ b1,
    const float* __restrict__ b2, void* __restrict__ out0,
    void* __restrict__ out1, void* __restrict__ out2) {
    const int K = DD;
    __shared__ __align__(16) bf16 As[128 * 32];
    __shared__ __align__(16) bf16 Bs[128 * 32];
    __shared__ __align__(16) bf16 Cs[MODE == 0 ? 128 * 136 : 1]; // epilogue stage

    int m0 = blockIdx.x * 128;
    int n0 = blockIdx.y * 128;

    const bf16* Wz;
    const float* bias;
    void* out;
    float scale = 1.0f;
    int z = 0;
    if (MODE == 0) {
        z = blockIdx.z;
        Wz = Wt + (size_t)z * DD * DD;
        bias = (z == 0) ? b0 : ((z == 1) ? b1 : b2);
        out = (z == 0) ? out0 : ((z == 1) ? out1 : out2);
        if (z == 0) scale = 0.125f * 1.44269504f; // (1/sqrt(HD)) * log2(e)
    } else {
        Wz = Wt; bias = b0; out = out0;
    }

    int tid = threadIdx.x;
    int w = tid >> 6, lane = tid & 63;
    int wm = w >> 1, wn = w & 1;
    int quad = lane >> 4, l16 = lane & 15;

    f32x4 acc[4][4];
#pragma unroll
    for (int i = 0; i < 4; i++)
#pragma unroll
        for (int j = 0; j < 4; j++) acc[i][j] = (f32x4){0.f, 0.f, 0.f, 0.f};

    for (int k0 = 0; k0 < K; k0 += 32) {
        __syncthreads(); // previous iteration's LDS reads complete
#pragma unroll
        for (int j = 0; j < 2; j++) {
            int c = j * 256 + w * 64 + lane; // lds dest contiguous per wave
            int row = c >> 2, kk = (c & 3) * 8;
            async_copy16(&As[c * 8], &A[(size_t)(m0 + row) * K + k0 + kk]);
            async_copy16(&Bs[c * 8], &Wz[(size_t)(n0 + row) * K + k0 + kk]);
        }
        __syncthreads(); // drains vmcnt(0) before barrier

        bf16x8 af[4], bfm[4];
#pragma unroll
        for (int i = 0; i < 4; i++) {
            af[i] = *(const bf16x8*)&As[(wm * 64 + i * 16 + l16) * 32 + quad * 8];
            bfm[i] = *(const bf16x8*)&Bs[(wn * 64 + i * 16 + l16) * 32 + quad * 8];
        }
#pragma unroll
        for (int i = 0; i < 4; i++)
#pragma unroll
            for (int j = 0; j < 4; j++)
                acc[i][j] = __builtin_amdgcn_mfma_f32_16x16x32_bf16(
                    af[i], bfm[j], acc[i][j], 0, 0, 0);
    }

    // Epilogue. C/D layout: col = lane&15, row = quad*4 + reg.
    if (MODE == 0) {
        // Stage bias-applied bf16 C-tile into LDS.
        // z<2: Cs[m_local*136 + n_local];  z==2: transposed Cs[n_local*136 + m_local]
#pragma unroll
        for (int j = 0; j < 4; j++) {
            int nl = wn * 64 + j * 16 + l16;
            float bv = bias[n0 + nl];
#pragma unroll
            for (int i = 0; i < 4; i++) {
#pragma unroll
                for (int r = 0; r < 4; r++) {
                    int ml = wm * 64 + i * 16 + quad * 4 + r;
                    bf16 v = (bf16)((acc[i][j][r] + bv) * scale);
                    if (z == 2) Cs[nl * 136 + ml] = v;
                    else        Cs[ml * 136 + nl] = v;
                }
            }
        }
        __syncthreads();

        int bidx = m0 >> 11;          // batch (tile never crosses batch)
        int tok0 = m0 & (NN - 1);
        int hh0 = n0 >> 6;            // first of the 2 heads this tile covers
        if (z != 2) {
            // out [bh][tok][hd]: per head, (tok,hd) is one contiguous 16KB run.
#pragma unroll
            for (int hf = 0; hf < 2; hf++) {
                bf16* base = (bf16*)out + ((size_t)(bidx * HH + hh0 + hf) * NN + tok0) * HD;
#pragma unroll
                for (int k = 0; k < 4; k++) {
                    int f = k * 2048 + tid * 8;       // 0..8191, tok=f>>6, hd=f&63
                    int tok = f >> 6, hd = f & 63;
                    *(bf16x8*)&base[f] = *(const bf16x8*)&Cs[tok * 136 + hf * 64 + hd];
                }
            }
        } else {
            // V^T out [bh][hd][tok]: per (head,hd), tok-row is contiguous 256B.
#pragma unroll
            for (int hf = 0; hf < 2; hf++) {
#pragma unroll
                for (int k = 0; k < 4; k++) {
                    int hd = k * 16 + (tid >> 4);     // 0..63
                    int tk = (tid & 15) * 8;
                    bf16* dst = (bf16*)out +
                        ((size_t)(bidx * HH + hh0 + hf) * HD + hd) * NN + tok0 + tk;
                    *(bf16x8*)dst = *(const bf16x8*)&Cs[(hf * 64 + hd) * 136 + tk];
                }
            }
        }
    } else {
#pragma unroll
        for (int j = 0; j < 4; j++) {
            int n = n0 + wn * 64 + j * 16 + l16;
            float bv = bias[n];
#pragma unroll
            for (int i = 0; i < 4; i++) {
                int mrow = m0 + wm * 64 + i * 16 + quad * 4;
#pragma unroll
                for (int r = 0; r < 4; r++)
                    ((float*)out)[(size_t)(mrow + r) * DD + n] = acc[i][j][r] + bv;
            }
        }
    }
}

// ---------------------------------------------------------------------------
// Flash attention (causal, no-max softmax) — R14: P-in-registers, 4 blocks/CU.
// grid = (B*H, 16), block = 512 threads (8 waves x 16 q-rows = 128-row q-tile).
// bh on blockIdx.x: linear id%8 == bh%8 -> all q-blocks of a head share one
// XCD's L2. One q-tile per block; qi permuted over blockIdx.y so the 4 blocks
// a CU hosts (same bh, y%4 fixed, y>>2 = 0..3) sum to 34 tile-iters, and the
// longest tiles dispatch first.
// Swapped QK^T: s = mfma(K,Q) -> lane holds P[q=l16][kv=16ni+quad*4+r], which
// is exactly the A-frag of mfma_f32_16x16x16_bf16 (m=l16, k=quad*4+j).
// P goes straight from registers into the K=16 PV MFMA; no P LDS buffer.
// Per tile: barrier -> ds_write(prefetched regs) -> barrier -> issue loads
// for t+1 -> compute t (load latency hidden behind compute).
// ---------------------------------------------------------------------------
__global__ __launch_bounds__(512, 4) void flash_attn(
    const bf16* __restrict__ Q, const bf16* __restrict__ Kg,
    const bf16* __restrict__ Vt_g, bf16* __restrict__ Oc) {
    __shared__ __align__(16) bf16 Ks[128 * 72];   // [kv][hd], stride 72
    __shared__ __align__(16) bf16 Vs[64 * 136];   // [d][kv], stride 136

    int bh = blockIdx.x;              // linear id % 8 == bh % 8 -> XCD locality
    int b = bh >> 4, h = bh & 15;
    int tid = threadIdx.x;
    int w = tid >> 6, lane = tid & 63;
    int quad = lane >> 4, l16 = lane & 15;

    // Balanced qi permutation: CU's resident blocks share bh and ya=y&3,
    // differ in bp=y>>2 -> qi set {15-ya, 11-ya, 4+ya, ya}, sum 30 (34 iters).
    int y = blockIdx.y;
    int ya = y & 3, bp = 3 - (y >> 2);
    int qi = (bp < 2) ? (4 * bp + ya) : (4 * bp + 3 - ya);
    int q0 = qi * 128;

    const bf16* Qb = Q + (size_t)bh * NN * HD;
    const bf16* Kb = Kg + (size_t)bh * NN * HD;
    const bf16* Vtb = Vt_g + (size_t)bh * HD * NN;

    const short4v ones16 = {0x3F80, 0x3F80, 0x3F80, 0x3F80}; // bf16 1.0 x4

    // Per-thread staging coordinates (fixed across tiles). 512 threads stage
    // a 128x64 K-tile and a 64x128 V^T-tile with 2 b128 chunks each.
    int kr[2], kc[2], vd[2], vk[2];
#pragma unroll
    for (int j = 0; j < 2; j++) {
        int c = j * 512 + tid;
        kr[j] = c >> 3; kc[j] = (c & 7) * 8;   // K: row, col-chunk
        vd[j] = c >> 4; vk[j] = (c & 15) * 8;  // V^T: d, kv-chunk
    }

    int qrow = q0 + w * 16 + l16;              // this lane's q (qf col & mask)

    // This wave's Q fragments (B-operand for swapped mfma: col=l16=q,
    // k = ks*32 + quad*8 + j over HD).
    bf16x8 qf[2];
#pragma unroll
    for (int ks = 0; ks < 2; ks++)
        qf[ks] = *(const bf16x8*)&Qb[(size_t)qrow * HD + ks * 32 + quad * 8];

    f32x4 l_sum = (f32x4){0.f, 0.f, 0.f, 0.f};
    f32x4 o_acc[4];
#pragma unroll
    for (int di = 0; di < 4; di++) o_acc[di] = (f32x4){0.f, 0.f, 0.f, 0.f};

    // Preload tile 0 into registers.
    bf16x8 kreg[2], vreg[2];
#pragma unroll
    for (int j = 0; j < 2; j++) {
        kreg[j] = *(const bf16x8*)&Kb[(size_t)kr[j] * HD + kc[j]];
        vreg[j] = *(const bf16x8*)&Vtb[(size_t)vd[j] * NN + vk[j]];
    }

    for (int t = 0; t <= qi; t++) {
        __syncthreads(); // previous iteration's LDS reads complete
        // Commit prefetched tile t to LDS.
#pragma unroll
        for (int j = 0; j < 2; j++) {
            *(bf16x8*)&Ks[kr[j] * 72 + kc[j]] = kreg[j];
            *(bf16x8*)&Vs[vd[j] * 136 + vk[j]] = vreg[j];
        }
        __syncthreads();

        // Issue loads for tile t+1 (latency overlaps compute below).
        if (t < qi) {
            int kvn = (t + 1) * 128;
#pragma unroll
            for (int j = 0; j < 2; j++) {
                kreg[j] = *(const bf16x8*)&Kb[(size_t)(kvn + kr[j]) * HD + kc[j]];
                vreg[j] = *(const bf16x8*)&Vtb[(size_t)vd[j] * NN + kvn + vk[j]];
            }
        }

        int kv0 = t * 128;
        bool diag = (t == qi);
        // S^T = K * Q^T per 16-kv band. C-layout: row=kv=quad*4+r, col=q=l16.
#pragma unroll
        for (int ni = 0; ni < 8; ni++) {
            bf16x8 bk0 = *(const bf16x8*)&Ks[(ni * 16 + l16) * 72 + quad * 8];
            bf16x8 bk1 = *(const bf16x8*)&Ks[(ni * 16 + l16) * 72 + 32 + quad * 8];
            f32x4 s = (f32x4){0.f, 0.f, 0.f, 0.f};
            s = __builtin_amdgcn_mfma_f32_16x16x32_bf16(bk0, qf[0], s, 0, 0, 0);
            s = __builtin_amdgcn_mfma_f32_16x16x32_bf16(bk1, qf[1], s, 0, 0, 0);
            // lane holds S[qrow][kv0 + ni*16 + quad*4 + r], r=0..3 == the
            // A-fragment rows of the K=16 PV mfma. Exp + cvt, stay in regs.
            bf16x4 pb;
            if (diag) {
                int kvb = kv0 + ni * 16 + quad * 4;
#pragma unroll
                for (int r = 0; r < 4; r++)
                    pb[r] = (bf16)((kvb + r > qrow) ? 0.f : exp2f(s[r]));
            } else {
#pragma unroll
                for (int r = 0; r < 4; r++) pb[r] = (bf16)exp2f(s[r]);
            }
            short4v pv = __builtin_bit_cast(short4v, pb);
            // Row-sum via K=16 MFMA against ones (C row=quad*4+r matches o_acc).
            l_sum = mfma16x16x16(pv, ones16, l_sum);
            // PV: B-frag = V[kv=quad*4+j][d=di*16+l16] from V^T rows (b64 reads).
#pragma unroll
            for (int di = 0; di < 4; di++) {
                short4v vb = *(const short4v*)&Vs[(di * 16 + l16) * 136 + ni * 16 + quad * 4];
                o_acc[di] = mfma16x16x16(pv, vb, o_acc[di]);
            }
        }
    }

    // Epilogue: O/l -> [B, N, H*HD] (concat-head layout for the O-proj GEMM)
    // C-layout: row = q = quad*4 + r (within wave's 16), col = d = l16.
#pragma unroll
    for (int r = 0; r < 4; r++) {
        float inv = 1.0f / l_sum[r];
        int tok = q0 + w * 16 + quad * 4 + r;
#pragma unroll
        for (int di = 0; di < 4; di++) {
            int d = h * 64 + di * 16 + l16;
            Oc[((size_t)(b * NN + tok)) * DD + d] = (bf16)(o_acc[di][r] * inv);
        }
    }
}

// ---------------------------------------------------------------------------
extern "C" void kernel_launch(void* const* d_in, const int* in_sizes, int n_in,
                              void* d_out, int out_size, void* d_ws, size_t ws_size,
                              hipStream_t stream) {
    const float* x  = (const float*)d_in[0];
    const float* Wq = (const float*)d_in[1];
    const float* bq = (const float*)d_in[2];
    const float* Wk = (const float*)d_in[3];
    const float* bk = (const float*)d_in[4];
    const float* Wv = (const float*)d_in[5];
    const float* bv = (const float*)d_in[6];
    const float* Wo = (const float*)d_in[7];
    const float* bo = (const float*)d_in[8];

    const size_t need = (size_t)(8388608ull * 5 + 4194304ull) * sizeof(bf16);
    if (ws_size < need) return; // diagnostic: leaves d_out zeroed (absmax 3.8125)

    bf16* ws = (bf16*)d_ws;
    bf16* xb = ws;
    bf16* wt = xb + (size_t)MM * DD;
    bf16* Qw = wt + 4ull * DD * DD;       // [B*H, N, HD], pre-scaled 0.125*log2e
    bf16* Kw = Qw + (size_t)MM * DD;      // [B*H, N, HD]
    bf16* Vw = Kw + (size_t)MM * DD;      // V^T [B*H, HD, N]
    bf16* Aw = Vw + (size_t)MM * DD;      // attention out [B, N, D]

    convert_x<<<dim3(MM * DD / 1024), 256, 0, stream>>>(x, xb);

    transpose_w4<<<dim3(32, 32, 4), dim3(32, 8), 0, stream>>>(Wq, Wk, Wv, Wo, wt);

    gemm_bt<0><<<dim3(MM / 128, DD / 128, 3), 256, 0, stream>>>(
        xb, wt, bq, bk, bv, Qw, Kw, Vw);

    // grid (bh, qi-perm): bh%8 -> XCD affinity; 1024 blocks x 35840B LDS
    // x 64 VGPR -> 4 blocks/CU (8 waves/SIMD), CU-balanced via permutation.
    flash_attn<<<dim3(BB * HH, 16), 512, 0, stream>>>(Qw, Kw, Vw, Aw);

    gemm_bt<1><<<dim3(MM / 128, DD / 128, 1), 256, 0, stream>>>(
        Aw, wt + 3ull * DD * DD, bo, bo, bo, d_out, d_out, d_out);
}

// Round 6
// 265.745 us; speedup vs baseline: 1.3446x; 1.0361x over previous
//
#include <hip/hip_runtime.h>
#include <hip/hip_bf16.h>

// MultiHeadAttention: B=4, N=2048, D=1024, H=16, HD=64, causal.
// Contract: f32 inputs AND f32 output; bf16 internal compute.
// R15:
//  - flash: PV + row-sum at K=32 (band-pair concat of the verified per-band
//    P fragment; (quad,j)->kv map identical on A and B operands). MFMA per
//    wave-tile-iter 56 -> 36. Grid (bh, 8) paired qi/15-qi: XCD affinity
//    (linear id%8 == bh%8) AND every block exactly 17 tile-iters (R14's
//    lesson: occupancy is a time integral; unequal block lengths drain).
//  - gemm MODE0: Cs aliased over As+Bs (Cs live only post-K-loop; barrier
//    added). LDS 51200 -> 34816 B => 3 -> 4 blocks/CU.

#define BB 4
#define NN 2048
#define DD 1024
#define HH 16
#define HD 64
#define MM (BB * NN) // 8192

typedef __bf16 bf16;
typedef __bf16 bf16x4 __attribute__((ext_vector_type(4)));
typedef __bf16 bf16x8 __attribute__((ext_vector_type(8)));
typedef float f32x4 __attribute__((ext_vector_type(4)));

// Async 16B global->LDS copy. LDS dest must follow wave-uniform base + lane*16.
__device__ __forceinline__ void async_copy16(bf16* lds, const bf16* g) {
    __builtin_amdgcn_global_load_lds(
        (const __attribute__((address_space(1))) void*)g,
        (__attribute__((address_space(3))) void*)lds, 16, 0, 0);
}

// ---------------------------------------------------------------------------
// x: f32 [B*N*D] -> bf16
// ---------------------------------------------------------------------------
__global__ void convert_x(const float* __restrict__ x, bf16* __restrict__ xb) {
    int i = (blockIdx.x * 256 + threadIdx.x) * 4;
    float4 v = *(const float4*)&x[i];
    xb[i + 0] = (bf16)v.x;
    xb[i + 1] = (bf16)v.y;
    xb[i + 2] = (bf16)v.z;
    xb[i + 3] = (bf16)v.w;
}

// ---------------------------------------------------------------------------
// Weight transpose + convert (all 4 weights in one launch, z selects):
// Wt[z][n][k] = (bf16)W_z[k][n]  (D x D)
// ---------------------------------------------------------------------------
__global__ void transpose_w4(const float* __restrict__ W0, const float* __restrict__ W1,
                             const float* __restrict__ W2, const float* __restrict__ W3,
                             bf16* __restrict__ Wt) {
    __shared__ float tile[32][33];
    const float* W = (blockIdx.z == 0) ? W0 : (blockIdx.z == 1) ? W1
                    : (blockIdx.z == 2) ? W2 : W3;
    bf16* out = Wt + (size_t)blockIdx.z * DD * DD;
    int tx = threadIdx.x, ty = threadIdx.y;
    int x0 = blockIdx.x * 32, y0 = blockIdx.y * 32;
#pragma unroll
    for (int i = 0; i < 32; i += 8)
        tile[ty + i][tx] = W[(size_t)(y0 + ty + i) * DD + x0 + tx];
    __syncthreads();
#pragma unroll
    for (int i = 0; i < 32; i += 8)
        out[(size_t)(x0 + ty + i) * DD + y0 + tx] = (bf16)tile[tx][ty + i];
}

// ---------------------------------------------------------------------------
// GEMM: C[M,N] = A[M,K] * W[K,N] + bias, via Wt[N,K] (B^T form), bf16 MFMA.
// 128x128 block tile, 4 waves in 2x2, each wave 64x64 (4x4 MFMA 16x16x32).
// MODE 0: QKV fused (z==0 Q: scaled by 0.125*log2e for exp2 softmax).
//         z==0/1 (Q,K): bf16 out [B*H, N, HD]; z==2 (V): bf16 out [B*H, HD, N].
//         Epilogue staged through LDS (aliased over As/Bs; barrier guards).
// MODE 1: out-projection, f32 output, plain [M, N].
// ---------------------------------------------------------------------------
template <int MODE>
__global__ __launch_bounds__(256) void gemm_bt(
    const bf16* __restrict__ A, const bf16* __restrict__ Wt,
    const float* __restrict__ b0, const float* __restrict__ b1,
    const float* __restrict__ b2, void* __restrict__ out0,
    void* __restrict__ out1, void* __restrict__ out2) {
    const int K = DD;
    // MODE0: one buffer; As+Bs (16384 elems) live in K-loop, Cs (17408 elems)
    // lives only in the epilogue (post-barrier) -> union. 34816 B => 4 blk/CU.
    __shared__ __align__(16) bf16 smem[MODE == 0 ? 128 * 136 : 128 * 64];
    bf16* As = smem;
    bf16* Bs = smem + 128 * 32;
    bf16* Cs = smem; // MODE 0 epilogue alias

    int m0 = blockIdx.x * 128;
    int n0 = blockIdx.y * 128;

    const bf16* Wz;
    const float* bias;
    void* out;
    float scale = 1.0f;
    int z = 0;
    if (MODE == 0) {
        z = blockIdx.z;
        Wz = Wt + (size_t)z * DD * DD;
        bias = (z == 0) ? b0 : ((z == 1) ? b1 : b2);
        out = (z == 0) ? out0 : ((z == 1) ? out1 : out2);
        if (z == 0) scale = 0.125f * 1.44269504f; // (1/sqrt(HD)) * log2(e)
    } else {
        Wz = Wt; bias = b0; out = out0;
    }

    int tid = threadIdx.x;
    int w = tid >> 6, lane = tid & 63;
    int wm = w >> 1, wn = w & 1;
    int quad = lane >> 4, l16 = lane & 15;

    f32x4 acc[4][4];
#pragma unroll
    for (int i = 0; i < 4; i++)
#pragma unroll
        for (int j = 0; j < 4; j++) acc[i][j] = (f32x4){0.f, 0.f, 0.f, 0.f};

    for (int k0 = 0; k0 < K; k0 += 32) {
        __syncthreads(); // previous iteration's LDS reads complete
#pragma unroll
        for (int j = 0; j < 2; j++) {
            int c = j * 256 + w * 64 + lane; // lds dest contiguous per wave
            int row = c >> 2, kk = (c & 3) * 8;
            async_copy16(&As[c * 8], &A[(size_t)(m0 + row) * K + k0 + kk]);
            async_copy16(&Bs[c * 8], &Wz[(size_t)(n0 + row) * K + k0 + kk]);
        }
        __syncthreads(); // drains vmcnt(0) before barrier

        bf16x8 af[4], bfm[4];
#pragma unroll
        for (int i = 0; i < 4; i++) {
            af[i] = *(const bf16x8*)&As[(wm * 64 + i * 16 + l16) * 32 + quad * 8];
            bfm[i] = *(const bf16x8*)&Bs[(wn * 64 + i * 16 + l16) * 32 + quad * 8];
        }
#pragma unroll
        for (int i = 0; i < 4; i++)
#pragma unroll
            for (int j = 0; j < 4; j++)
                acc[i][j] = __builtin_amdgcn_mfma_f32_16x16x32_bf16(
                    af[i], bfm[j], acc[i][j], 0, 0, 0);
    }

    // Epilogue. C/D layout: col = lane&15, row = quad*4 + reg.
    if (MODE == 0) {
        __syncthreads(); // all waves' As/Bs reads done before Cs overwrites
        // Stage bias-applied bf16 C-tile into LDS.
        // z<2: Cs[m_local*136 + n_local];  z==2: transposed Cs[n_local*136 + m_local]
#pragma unroll
        for (int j = 0; j < 4; j++) {
            int nl = wn * 64 + j * 16 + l16;
            float bv = bias[n0 + nl];
#pragma unroll
            for (int i = 0; i < 4; i++) {
#pragma unroll
                for (int r = 0; r < 4; r++) {
                    int ml = wm * 64 + i * 16 + quad * 4 + r;
                    bf16 v = (bf16)((acc[i][j][r] + bv) * scale);
                    if (z == 2) Cs[nl * 136 + ml] = v;
                    else        Cs[ml * 136 + nl] = v;
                }
            }
        }
        __syncthreads();

        int bidx = m0 >> 11;          // batch (tile never crosses batch)
        int tok0 = m0 & (NN - 1);
        int hh0 = n0 >> 6;            // first of the 2 heads this tile covers
        if (z != 2) {
            // out [bh][tok][hd]: per head, (tok,hd) is one contiguous 16KB run.
#pragma unroll
            for (int hf = 0; hf < 2; hf++) {
                bf16* base = (bf16*)out + ((size_t)(bidx * HH + hh0 + hf) * NN + tok0) * HD;
#pragma unroll
                for (int k = 0; k < 4; k++) {
                    int f = k * 2048 + tid * 8;       // 0..8191, tok=f>>6, hd=f&63
                    int tok = f >> 6, hd = f & 63;
                    *(bf16x8*)&base[f] = *(const bf16x8*)&Cs[tok * 136 + hf * 64 + hd];
                }
            }
        } else {
            // V^T out [bh][hd][tok]: per (head,hd), tok-row is contiguous 256B.
#pragma unroll
            for (int hf = 0; hf < 2; hf++) {
#pragma unroll
                for (int k = 0; k < 4; k++) {
                    int hd = k * 16 + (tid >> 4);     // 0..63
                    int tk = (tid & 15) * 8;
                    bf16* dst = (bf16*)out +
                        ((size_t)(bidx * HH + hh0 + hf) * HD + hd) * NN + tok0 + tk;
                    *(bf16x8*)dst = *(const bf16x8*)&Cs[(hf * 64 + hd) * 136 + tk];
                }
            }
        }
    } else {
#pragma unroll
        for (int j = 0; j < 4; j++) {
            int n = n0 + wn * 64 + j * 16 + l16;
            float bv = bias[n];
#pragma unroll
            for (int i = 0; i < 4; i++) {
                int mrow = m0 + wm * 64 + i * 16 + quad * 4;
#pragma unroll
                for (int r = 0; r < 4; r++)
                    ((float*)out)[(size_t)(mrow + r) * DD + n] = acc[i][j][r] + bv;
            }
        }
    }
}

// ---------------------------------------------------------------------------
// Flash attention (causal, no-max softmax) — R15: P-in-registers, K=32 PV.
// grid = (B*H, 8), block = 512 threads (8 waves x 16 q-rows = 128-row q-tile).
// bh on blockIdx.x -> linear id%8 == bh%8 -> XCD L2 affinity for K/V.
// Block does q-tiles qi=blockIdx.y and 15-blockIdx.y: every block exactly
// 17 tile-iters (balanced; occupancy is a time integral — R14 lesson).
// Swapped QK^T: s = mfma(K,Q) -> lane holds P[q=l16][kv=band*16+quad*4+r].
// PV at K=32: A-frag = concat(band 2mi, band 2mi+1) P values (j=0..3 band a,
// j=4..7 band b); B-frag = two b64 V^T reads (kv=32mi+quad*4, +16). The
// (quad,j)->kv map is bijective and identical on A and B => exact contraction.
// Row-sum via same K=32 MFMA against ones.
// Per tile: barrier -> ds_write(prefetched regs) -> barrier -> issue loads
// for t+1 -> compute t (load latency hidden behind compute).
// ---------------------------------------------------------------------------
__global__ __launch_bounds__(512, 4) void flash_attn(
    const bf16* __restrict__ Q, const bf16* __restrict__ Kg,
    const bf16* __restrict__ Vt_g, bf16* __restrict__ Oc) {
    __shared__ __align__(16) bf16 Ks[128 * 72];   // [kv][hd], stride 72
    __shared__ __align__(16) bf16 Vs[64 * 136];   // [d][kv], stride 136

    int bh = blockIdx.x;              // linear id % 8 == bh % 8 -> XCD locality
    int b = bh >> 4, h = bh & 15;
    int tid = threadIdx.x;
    int w = tid >> 6, lane = tid & 63;
    int quad = lane >> 4, l16 = lane & 15;

    const bf16* Qb = Q + (size_t)bh * NN * HD;
    const bf16* Kb = Kg + (size_t)bh * NN * HD;
    const bf16* Vtb = Vt_g + (size_t)bh * HD * NN;

    bf16x8 ones8;
#pragma unroll
    for (int i = 0; i < 8; i++) ones8[i] = (bf16)1.0f;

    // Per-thread staging coordinates (fixed across tiles). 512 threads stage
    // a 128x64 K-tile and a 64x128 V^T-tile with 2 b128 chunks each.
    int kr[2], kc[2], vd[2], vk[2];
#pragma unroll
    for (int j = 0; j < 2; j++) {
        int c = j * 512 + tid;
        kr[j] = c >> 3; kc[j] = (c & 7) * 8;   // K: row, col-chunk
        vd[j] = c >> 4; vk[j] = (c & 15) * 8;  // V^T: d, kv-chunk
    }

    for (int phase = 0; phase < 2; phase++) {
        int qi = (phase == 0) ? blockIdx.y : (15 - blockIdx.y);
        int q0 = qi * 128;
        int qrow = q0 + w * 16 + l16;          // this lane's q (qf col & mask)

        // This wave's Q fragments (B-operand for swapped mfma: col=l16=q,
        // k = ks*32 + quad*8 + j over HD).
        bf16x8 qf[2];
#pragma unroll
        for (int ks = 0; ks < 2; ks++)
            qf[ks] = *(const bf16x8*)&Qb[(size_t)qrow * HD + ks * 32 + quad * 8];

        f32x4 l_sum = (f32x4){0.f, 0.f, 0.f, 0.f};
        f32x4 o_acc[4];
#pragma unroll
        for (int di = 0; di < 4; di++) o_acc[di] = (f32x4){0.f, 0.f, 0.f, 0.f};

        // Preload tile 0 into registers.
        bf16x8 kreg[2], vreg[2];
#pragma unroll
        for (int j = 0; j < 2; j++) {
            kreg[j] = *(const bf16x8*)&Kb[(size_t)kr[j] * HD + kc[j]];
            vreg[j] = *(const bf16x8*)&Vtb[(size_t)vd[j] * NN + vk[j]];
        }

        for (int t = 0; t <= qi; t++) {
            __syncthreads(); // previous iteration's LDS reads complete
            // Commit prefetched tile t to LDS.
#pragma unroll
            for (int j = 0; j < 2; j++) {
                *(bf16x8*)&Ks[kr[j] * 72 + kc[j]] = kreg[j];
                *(bf16x8*)&Vs[vd[j] * 136 + vk[j]] = vreg[j];
            }
            __syncthreads();

            // Issue loads for tile t+1 (latency overlaps compute below).
            if (t < qi) {
                int kvn = (t + 1) * 128;
#pragma unroll
                for (int j = 0; j < 2; j++) {
                    kreg[j] = *(const bf16x8*)&Kb[(size_t)(kvn + kr[j]) * HD + kc[j]];
                    vreg[j] = *(const bf16x8*)&Vtb[(size_t)vd[j] * NN + kvn + vk[j]];
                }
            }

            int kv0 = t * 128;
            bool diag = (t == qi);
            // Per 32-kv band-pair mi: bands a=2mi, b=2mi+1.
#pragma unroll
            for (int mi = 0; mi < 4; mi++) {
                int ba = 2 * mi, bb = 2 * mi + 1;
                bf16x8 ka0 = *(const bf16x8*)&Ks[(ba * 16 + l16) * 72 + quad * 8];
                bf16x8 ka1 = *(const bf16x8*)&Ks[(ba * 16 + l16) * 72 + 32 + quad * 8];
                bf16x8 kb0 = *(const bf16x8*)&Ks[(bb * 16 + l16) * 72 + quad * 8];
                bf16x8 kb1 = *(const bf16x8*)&Ks[(bb * 16 + l16) * 72 + 32 + quad * 8];
                f32x4 sa = (f32x4){0.f, 0.f, 0.f, 0.f};
                f32x4 sb = (f32x4){0.f, 0.f, 0.f, 0.f};
                sa = __builtin_amdgcn_mfma_f32_16x16x32_bf16(ka0, qf[0], sa, 0, 0, 0);
                sa = __builtin_amdgcn_mfma_f32_16x16x32_bf16(ka1, qf[1], sa, 0, 0, 0);
                sb = __builtin_amdgcn_mfma_f32_16x16x32_bf16(kb0, qf[0], sb, 0, 0, 0);
                sb = __builtin_amdgcn_mfma_f32_16x16x32_bf16(kb1, qf[1], sb, 0, 0, 0);
                // lane holds S[qrow][kv0 + band*16 + quad*4 + r], r=0..3.
                bf16x4 pa4, pb4;
                if (diag) {
                    int kva = kv0 + ba * 16 + quad * 4;
                    int kvb = kv0 + bb * 16 + quad * 4;
#pragma unroll
                    for (int r = 0; r < 4; r++) {
                        pa4[r] = (bf16)((kva + r > qrow) ? 0.f : exp2f(sa[r]));
                        pb4[r] = (bf16)((kvb + r > qrow) ? 0.f : exp2f(sb[r]));
                    }
                } else {
#pragma unroll
                    for (int r = 0; r < 4; r++) {
                        pa4[r] = (bf16)exp2f(sa[r]);
                        pb4[r] = (bf16)exp2f(sb[r]);
                    }
                }
                // K=32 A-frag: j=0..3 -> band a (kv=32mi+quad*4+j),
                //              j=4..7 -> band b (kv=32mi+16+quad*4+(j-4)).
                bf16x8 pfrag = __builtin_shufflevector(pa4, pb4, 0, 1, 2, 3, 4, 5, 6, 7);
                l_sum = __builtin_amdgcn_mfma_f32_16x16x32_bf16(pfrag, ones8, l_sum, 0, 0, 0);
                // B-frag: V[kv map identical to A] x [d=di*16+l16], two b64s.
#pragma unroll
                for (int di = 0; di < 4; di++) {
                    const bf16* vrow = &Vs[(di * 16 + l16) * 136 + mi * 32 + quad * 4];
                    bf16x4 vlo = *(const bf16x4*)(vrow);
                    bf16x4 vhi = *(const bf16x4*)(vrow + 16);
                    bf16x8 vfrag = __builtin_shufflevector(vlo, vhi, 0, 1, 2, 3, 4, 5, 6, 7);
                    o_acc[di] = __builtin_amdgcn_mfma_f32_16x16x32_bf16(pfrag, vfrag, o_acc[di], 0, 0, 0);
                }
            }
        }

        // Epilogue: O/l -> [B, N, H*HD] (concat-head layout for the O-proj GEMM)
        // C-layout: row = q = quad*4 + r (within wave's 16), col = d = l16.
#pragma unroll
        for (int r = 0; r < 4; r++) {
            float inv = 1.0f / l_sum[r];
            int tok = q0 + w * 16 + quad * 4 + r;
#pragma unroll
            for (int di = 0; di < 4; di++) {
                int d = h * 64 + di * 16 + l16;
                Oc[((size_t)(b * NN + tok)) * DD + d] = (bf16)(o_acc[di][r] * inv);
            }
        }
    }
}

// ---------------------------------------------------------------------------
extern "C" void kernel_launch(void* const* d_in, const int* in_sizes, int n_in,
                              void* d_out, int out_size, void* d_ws, size_t ws_size,
                              hipStream_t stream) {
    const float* x  = (const float*)d_in[0];
    const float* Wq = (const float*)d_in[1];
    const float* bq = (const float*)d_in[2];
    const float* Wk = (const float*)d_in[3];
    const float* bk = (const float*)d_in[4];
    const float* Wv = (const float*)d_in[5];
    const float* bv = (const float*)d_in[6];
    const float* Wo = (const float*)d_in[7];
    const float* bo = (const float*)d_in[8];

    const size_t need = (size_t)(8388608ull * 5 + 4194304ull) * sizeof(bf16);
    if (ws_size < need) return; // diagnostic: leaves d_out zeroed (absmax 3.8125)

    bf16* ws = (bf16*)d_ws;
    bf16* xb = ws;
    bf16* wt = xb + (size_t)MM * DD;
    bf16* Qw = wt + 4ull * DD * DD;       // [B*H, N, HD], pre-scaled 0.125*log2e
    bf16* Kw = Qw + (size_t)MM * DD;      // [B*H, N, HD]
    bf16* Vw = Kw + (size_t)MM * DD;      // V^T [B*H, HD, N]
    bf16* Aw = Vw + (size_t)MM * DD;      // attention out [B, N, D]

    convert_x<<<dim3(MM * DD / 1024), 256, 0, stream>>>(x, xb);

    transpose_w4<<<dim3(32, 32, 4), dim3(32, 8), 0, stream>>>(Wq, Wk, Wv, Wo, wt);

    gemm_bt<0><<<dim3(MM / 128, DD / 128, 3), 256, 0, stream>>>(
        xb, wt, bq, bk, bv, Qw, Kw, Vw);

    // grid (bh, 8): bh%8 -> XCD affinity; paired qi/15-qi -> every block
    // exactly 17 tile-iters (balanced residency).
    flash_attn<<<dim3(BB * HH, 8), 512, 0, stream>>>(Qw, Kw, Vw, Aw);

    gemm_bt<1><<<dim3(MM / 128, DD / 128, 1), 256, 0, stream>>>(
        Aw, wt + 3ull * DD * DD, bo, bo, bo, d_out, d_out, d_out);
}

// Round 7
// 251.586 us; speedup vs baseline: 1.4203x; 1.0563x over previous
//
#include <hip/hip_runtime.h>
#include <hip/hip_bf16.h>

// MultiHeadAttention: B=4, N=2048, D=1024, H=16, HD=64, causal.
// Contract: f32 inputs AND f32 output; bf16 internal compute.
// R16 = R15 +
//  - flash double-buffered K/V, ONE barrier per tile-iter: [issue loads t+1 ->
//    compute t from buf(t&1) -> ds_write t+1 into other buf -> barrier].
//    ds_write overlaps compute; global latency hides under compute; the
//    [bar -> write-drain -> bar] sandwich is gone. LDS 35840 -> 71680 B
//    (still 2 blocks/CU = current effective residency).
//  - V^T stored kv-PERMUTED (baked into gemm z=2 epilogue): within each
//    32-token block, pos p holds orig o(p) = (p>>3)*4 + ((p>>2)&1)*16 + (p&3).
//    PV B-frag element j then equals the kv pfrag holds at j -> V read is a
//    single b128 (was 2x b64). P side unchanged (verified band-concat map).

#define BB 4
#define NN 2048
#define DD 1024
#define HH 16
#define HD 64
#define MM (BB * NN) // 8192

typedef __bf16 bf16;
typedef __bf16 bf16x4 __attribute__((ext_vector_type(4)));
typedef __bf16 bf16x8 __attribute__((ext_vector_type(8)));
typedef float f32x4 __attribute__((ext_vector_type(4)));

// Async 16B global->LDS copy. LDS dest must follow wave-uniform base + lane*16.
__device__ __forceinline__ void async_copy16(bf16* lds, const bf16* g) {
    __builtin_amdgcn_global_load_lds(
        (const __attribute__((address_space(1))) void*)g,
        (__attribute__((address_space(3))) void*)lds, 16, 0, 0);
}

// ---------------------------------------------------------------------------
// x: f32 [B*N*D] -> bf16
// ---------------------------------------------------------------------------
__global__ void convert_x(const float* __restrict__ x, bf16* __restrict__ xb) {
    int i = (blockIdx.x * 256 + threadIdx.x) * 4;
    float4 v = *(const float4*)&x[i];
    xb[i + 0] = (bf16)v.x;
    xb[i + 1] = (bf16)v.y;
    xb[i + 2] = (bf16)v.z;
    xb[i + 3] = (bf16)v.w;
}

// ---------------------------------------------------------------------------
// Weight transpose + convert (all 4 weights in one launch, z selects):
// Wt[z][n][k] = (bf16)W_z[k][n]  (D x D)
// ---------------------------------------------------------------------------
__global__ void transpose_w4(const float* __restrict__ W0, const float* __restrict__ W1,
                             const float* __restrict__ W2, const float* __restrict__ W3,
                             bf16* __restrict__ Wt) {
    __shared__ float tile[32][33];
    const float* W = (blockIdx.z == 0) ? W0 : (blockIdx.z == 1) ? W1
                    : (blockIdx.z == 2) ? W2 : W3;
    bf16* out = Wt + (size_t)blockIdx.z * DD * DD;
    int tx = threadIdx.x, ty = threadIdx.y;
    int x0 = blockIdx.x * 32, y0 = blockIdx.y * 32;
#pragma unroll
    for (int i = 0; i < 32; i += 8)
        tile[ty + i][tx] = W[(size_t)(y0 + ty + i) * DD + x0 + tx];
    __syncthreads();
#pragma unroll
    for (int i = 0; i < 32; i += 8)
        out[(size_t)(x0 + ty + i) * DD + y0 + tx] = (bf16)tile[tx][ty + i];
}

// ---------------------------------------------------------------------------
// GEMM: C[M,N] = A[M,K] * W[K,N] + bias, via Wt[N,K] (B^T form), bf16 MFMA.
// 128x128 block tile, 4 waves in 2x2, each wave 64x64 (4x4 MFMA 16x16x32).
// MODE 0: QKV fused (z==0 Q: scaled by 0.125*log2e for exp2 softmax).
//         z==0/1 (Q,K): bf16 out [B*H, N, HD];
//         z==2 (V): bf16 out [B*H, HD, N] with per-32-tok kv permutation
//         (see flash PV): pos p <- orig o(p) = (p>>3)*4 + ((p>>2)&1)*16 + (p&3).
//         Epilogue staged through LDS (aliased over As/Bs; barrier guards).
// MODE 1: out-projection, f32 output, plain [M, N].
// ---------------------------------------------------------------------------
template <int MODE>
__global__ __launch_bounds__(256) void gemm_bt(
    const bf16* __restrict__ A, const bf16* __restrict__ Wt,
    const float* __restrict__ b0, const float* __restrict__ b1,
    const float* __restrict__ b2, void* __restrict__ out0,
    void* __restrict__ out1, void* __restrict__ out2) {
    const int K = DD;
    // MODE0: one buffer; As+Bs (16384 elems) live in K-loop, Cs (17408 elems)
    // lives only in the epilogue (post-barrier) -> union. 34816 B => 4 blk/CU.
    __shared__ __align__(16) bf16 smem[MODE == 0 ? 128 * 136 : 128 * 64];
    bf16* As = smem;
    bf16* Bs = smem + 128 * 32;
    bf16* Cs = smem; // MODE 0 epilogue alias

    int m0 = blockIdx.x * 128;
    int n0 = blockIdx.y * 128;

    const bf16* Wz;
    const float* bias;
    void* out;
    float scale = 1.0f;
    int z = 0;
    if (MODE == 0) {
        z = blockIdx.z;
        Wz = Wt + (size_t)z * DD * DD;
        bias = (z == 0) ? b0 : ((z == 1) ? b1 : b2);
        out = (z == 0) ? out0 : ((z == 1) ? out1 : out2);
        if (z == 0) scale = 0.125f * 1.44269504f; // (1/sqrt(HD)) * log2(e)
    } else {
        Wz = Wt; bias = b0; out = out0;
    }

    int tid = threadIdx.x;
    int w = tid >> 6, lane = tid & 63;
    int wm = w >> 1, wn = w & 1;
    int quad = lane >> 4, l16 = lane & 15;

    f32x4 acc[4][4];
#pragma unroll
    for (int i = 0; i < 4; i++)
#pragma unroll
        for (int j = 0; j < 4; j++) acc[i][j] = (f32x4){0.f, 0.f, 0.f, 0.f};

    for (int k0 = 0; k0 < K; k0 += 32) {
        __syncthreads(); // previous iteration's LDS reads complete
#pragma unroll
        for (int j = 0; j < 2; j++) {
            int c = j * 256 + w * 64 + lane; // lds dest contiguous per wave
            int row = c >> 2, kk = (c & 3) * 8;
            async_copy16(&As[c * 8], &A[(size_t)(m0 + row) * K + k0 + kk]);
            async_copy16(&Bs[c * 8], &Wz[(size_t)(n0 + row) * K + k0 + kk]);
        }
        __syncthreads(); // drains vmcnt(0) before barrier

        bf16x8 af[4], bfm[4];
#pragma unroll
        for (int i = 0; i < 4; i++) {
            af[i] = *(const bf16x8*)&As[(wm * 64 + i * 16 + l16) * 32 + quad * 8];
            bfm[i] = *(const bf16x8*)&Bs[(wn * 64 + i * 16 + l16) * 32 + quad * 8];
        }
#pragma unroll
        for (int i = 0; i < 4; i++)
#pragma unroll
            for (int j = 0; j < 4; j++)
                acc[i][j] = __builtin_amdgcn_mfma_f32_16x16x32_bf16(
                    af[i], bfm[j], acc[i][j], 0, 0, 0);
    }

    // Epilogue. C/D layout: col = lane&15, row = quad*4 + reg.
    if (MODE == 0) {
        __syncthreads(); // all waves' As/Bs reads done before Cs overwrites
        // Stage bias-applied bf16 C-tile into LDS.
        // z<2: Cs[m_local*136 + n_local];  z==2: transposed Cs[n_local*136 + m_local]
#pragma unroll
        for (int j = 0; j < 4; j++) {
            int nl = wn * 64 + j * 16 + l16;
            float bv = bias[n0 + nl];
#pragma unroll
            for (int i = 0; i < 4; i++) {
#pragma unroll
                for (int r = 0; r < 4; r++) {
                    int ml = wm * 64 + i * 16 + quad * 4 + r;
                    bf16 v = (bf16)((acc[i][j][r] + bv) * scale);
                    if (z == 2) Cs[nl * 136 + ml] = v;
                    else        Cs[ml * 136 + nl] = v;
                }
            }
        }
        __syncthreads();

        int bidx = m0 >> 11;          // batch (tile never crosses batch)
        int tok0 = m0 & (NN - 1);
        int hh0 = n0 >> 6;            // first of the 2 heads this tile covers
        if (z != 2) {
            // out [bh][tok][hd]: per head, (tok,hd) is one contiguous 16KB run.
#pragma unroll
            for (int hf = 0; hf < 2; hf++) {
                bf16* base = (bf16*)out + ((size_t)(bidx * HH + hh0 + hf) * NN + tok0) * HD;
#pragma unroll
                for (int k = 0; k < 4; k++) {
                    int f = k * 2048 + tid * 8;       // 0..8191, tok=f>>6, hd=f&63
                    int tok = f >> 6, hd = f & 63;
                    *(bf16x8*)&base[f] = *(const bf16x8*)&Cs[tok * 136 + hf * 64 + hd];
                }
            }
        } else {
            // V^T out [bh][hd][tok], kv-permuted per 32-tok block:
            // dst pos p holds orig o(p) = (p>>3)*4 + ((p>>2)&1)*16 + (p&3).
            // For an 8-run p0..p0+7 (p0 mult of 8): o = base32 + qq*4
            // + (i>>2)*16 + (i&3), qq=(p0&31)>>3 -> two bf16x4 reads.
#pragma unroll
            for (int hf = 0; hf < 2; hf++) {
#pragma unroll
                for (int k = 0; k < 4; k++) {
                    int hd = k * 16 + (tid >> 4);     // 0..63
                    int p0 = (tid & 15) * 8;
                    int base32 = p0 & ~31;
                    int qq = (p0 & 31) >> 3;
                    const bf16* crow = &Cs[(hf * 64 + hd) * 136];
                    bf16x4 lo = *(const bf16x4*)&crow[base32 + qq * 4];
                    bf16x4 hi = *(const bf16x4*)&crow[base32 + qq * 4 + 16];
                    bf16x8 v = __builtin_shufflevector(lo, hi, 0, 1, 2, 3, 4, 5, 6, 7);
                    bf16* dst = (bf16*)out +
                        ((size_t)(bidx * HH + hh0 + hf) * HD + hd) * NN + tok0 + p0;
                    *(bf16x8*)dst = v;
                }
            }
        }
    } else {
#pragma unroll
        for (int j = 0; j < 4; j++) {
            int n = n0 + wn * 64 + j * 16 + l16;
            float bv = bias[n];
#pragma unroll
            for (int i = 0; i < 4; i++) {
                int mrow = m0 + wm * 64 + i * 16 + quad * 4;
#pragma unroll
                for (int r = 0; r < 4; r++)
                    ((float*)out)[(size_t)(mrow + r) * DD + n] = acc[i][j][r] + bv;
            }
        }
    }
}

// ---------------------------------------------------------------------------
// Flash attention (causal, no-max softmax) — R16: P-in-registers, K=32 PV,
// double-buffered K/V with ONE barrier per tile-iter.
// grid = (B*H, 8), block = 512 threads (8 waves x 16 q-rows = 128-row q-tile).
// bh on blockIdx.x -> linear id%8 == bh%8 -> XCD L2 affinity for K/V.
// Block does q-tiles qi=blockIdx.y and 15-blockIdx.y: every block exactly
// 17 tile-iters (balanced residency — occupancy is a time integral).
// Swapped QK^T: s = mfma(K,Q) -> lane holds P[q=l16][kv=band*16+quad*4+r].
// PV at K=32: pfrag = concat(band 2mi, band 2mi+1); V^T is kv-permuted in
// memory so the B-frag is ONE b128 whose element j matches pfrag's kv map.
// Per iter: [issue loads t+1 -> compute t from buf(t&1) -> ds_write t+1 into
// buf(t&1^1) -> barrier]: writes overlap compute, loads hide under compute.
// ---------------------------------------------------------------------------
__global__ __launch_bounds__(512, 4) void flash_attn(
    const bf16* __restrict__ Q, const bf16* __restrict__ Kg,
    const bf16* __restrict__ Vt_g, bf16* __restrict__ Oc) {
    __shared__ __align__(16) bf16 Ks[2][128 * 72];   // [kv][hd], stride 72
    __shared__ __align__(16) bf16 Vs[2][64 * 136];   // [d][kv-perm], stride 136

    int bh = blockIdx.x;              // linear id % 8 == bh % 8 -> XCD locality
    int b = bh >> 4, h = bh & 15;
    int tid = threadIdx.x;
    int w = tid >> 6, lane = tid & 63;
    int quad = lane >> 4, l16 = lane & 15;

    const bf16* Qb = Q + (size_t)bh * NN * HD;
    const bf16* Kb = Kg + (size_t)bh * NN * HD;
    const bf16* Vtb = Vt_g + (size_t)bh * HD * NN;

    bf16x8 ones8;
#pragma unroll
    for (int i = 0; i < 8; i++) ones8[i] = (bf16)1.0f;

    // Per-thread staging coordinates (fixed across tiles). 512 threads stage
    // a 128x64 K-tile and a 64x128 V^T-tile with 2 b128 chunks each.
    int kr[2], kc[2], vd[2], vk[2];
#pragma unroll
    for (int j = 0; j < 2; j++) {
        int c = j * 512 + tid;
        kr[j] = c >> 3; kc[j] = (c & 7) * 8;   // K: row, col-chunk
        vd[j] = c >> 4; vk[j] = (c & 15) * 8;  // V^T: d, kv-chunk
    }

    for (int phase = 0; phase < 2; phase++) {
        int qi = (phase == 0) ? blockIdx.y : (15 - blockIdx.y);
        int q0 = qi * 128;
        int qrow = q0 + w * 16 + l16;          // this lane's q (qf col & mask)

        // This wave's Q fragments (B-operand for swapped mfma: col=l16=q,
        // k = ks*32 + quad*8 + j over HD).
        bf16x8 qf[2];
#pragma unroll
        for (int ks = 0; ks < 2; ks++)
            qf[ks] = *(const bf16x8*)&Qb[(size_t)qrow * HD + ks * 32 + quad * 8];

        f32x4 l_sum = (f32x4){0.f, 0.f, 0.f, 0.f};
        f32x4 o_acc[4];
#pragma unroll
        for (int di = 0; di < 4; di++) o_acc[di] = (f32x4){0.f, 0.f, 0.f, 0.f};

        // Prologue: tile 0 -> regs -> buf 0 -> barrier.
        bf16x8 kreg[2], vreg[2];
#pragma unroll
        for (int j = 0; j < 2; j++) {
            kreg[j] = *(const bf16x8*)&Kb[(size_t)kr[j] * HD + kc[j]];
            vreg[j] = *(const bf16x8*)&Vtb[(size_t)vd[j] * NN + vk[j]];
        }
#pragma unroll
        for (int j = 0; j < 2; j++) {
            *(bf16x8*)&Ks[0][kr[j] * 72 + kc[j]] = kreg[j];
            *(bf16x8*)&Vs[0][vd[j] * 136 + vk[j]] = vreg[j];
        }
        __syncthreads();

        for (int t = 0; t <= qi; t++) {
            int cur = t & 1;
            // Issue loads for tile t+1 first (latency hides under compute).
            if (t < qi) {
                int kvn = (t + 1) * 128;
#pragma unroll
                for (int j = 0; j < 2; j++) {
                    kreg[j] = *(const bf16x8*)&Kb[(size_t)(kvn + kr[j]) * HD + kc[j]];
                    vreg[j] = *(const bf16x8*)&Vtb[(size_t)vd[j] * NN + kvn + vk[j]];
                }
            }

            const bf16* Kcur = Ks[cur];
            const bf16* Vcur = Vs[cur];
            int kv0 = t * 128;
            bool diag = (t == qi);
            // Per 32-kv band-pair mi: bands a=2mi, b=2mi+1.
#pragma unroll
            for (int mi = 0; mi < 4; mi++) {
                int ba = 2 * mi, bb = 2 * mi + 1;
                bf16x8 ka0 = *(const bf16x8*)&Kcur[(ba * 16 + l16) * 72 + quad * 8];
                bf16x8 ka1 = *(const bf16x8*)&Kcur[(ba * 16 + l16) * 72 + 32 + quad * 8];
                bf16x8 kb0 = *(const bf16x8*)&Kcur[(bb * 16 + l16) * 72 + quad * 8];
                bf16x8 kb1 = *(const bf16x8*)&Kcur[(bb * 16 + l16) * 72 + 32 + quad * 8];
                f32x4 sa = (f32x4){0.f, 0.f, 0.f, 0.f};
                f32x4 sb = (f32x4){0.f, 0.f, 0.f, 0.f};
                sa = __builtin_amdgcn_mfma_f32_16x16x32_bf16(ka0, qf[0], sa, 0, 0, 0);
                sa = __builtin_amdgcn_mfma_f32_16x16x32_bf16(ka1, qf[1], sa, 0, 0, 0);
                sb = __builtin_amdgcn_mfma_f32_16x16x32_bf16(kb0, qf[0], sb, 0, 0, 0);
                sb = __builtin_amdgcn_mfma_f32_16x16x32_bf16(kb1, qf[1], sb, 0, 0, 0);
                // lane holds S[qrow][kv0 + band*16 + quad*4 + r], r=0..3.
                bf16x4 pa4, pb4;
                if (diag) {
                    int kva = kv0 + ba * 16 + quad * 4;
                    int kvb = kv0 + bb * 16 + quad * 4;
#pragma unroll
                    for (int r = 0; r < 4; r++) {
                        pa4[r] = (bf16)((kva + r > qrow) ? 0.f : exp2f(sa[r]));
                        pb4[r] = (bf16)((kvb + r > qrow) ? 0.f : exp2f(sb[r]));
                    }
                } else {
#pragma unroll
                    for (int r = 0; r < 4; r++) {
                        pa4[r] = (bf16)exp2f(sa[r]);
                        pb4[r] = (bf16)exp2f(sb[r]);
                    }
                }
                // K=32 A-frag: j=0..3 -> band a (kv=32mi+quad*4+j),
                //              j=4..7 -> band b (kv=32mi+16+quad*4+(j-4)).
                bf16x8 pfrag = __builtin_shufflevector(pa4, pb4, 0, 1, 2, 3, 4, 5, 6, 7);
                l_sum = __builtin_amdgcn_mfma_f32_16x16x32_bf16(pfrag, ones8, l_sum, 0, 0, 0);
                // B-frag: ONE b128 — V^T kv-permuted in memory so position
                // quad*8+j holds V[same kv as pfrag element j][d].
#pragma unroll
                for (int di = 0; di < 4; di++) {
                    bf16x8 vfrag = *(const bf16x8*)&Vcur[(di * 16 + l16) * 136 + mi * 32 + quad * 8];
                    o_acc[di] = __builtin_amdgcn_mfma_f32_16x16x32_bf16(pfrag, vfrag, o_acc[di], 0, 0, 0);
                }
            }

            // Commit tile t+1 into the other buffer (overlaps nothing serial;
            // vmcnt wait for the loads lands here, hidden by compute above).
            if (t < qi) {
                bf16* Kn = Ks[cur ^ 1];
                bf16* Vn = Vs[cur ^ 1];
#pragma unroll
                for (int j = 0; j < 2; j++) {
                    *(bf16x8*)&Kn[kr[j] * 72 + kc[j]] = kreg[j];
                    *(bf16x8*)&Vn[vd[j] * 136 + vk[j]] = vreg[j];
                }
            }
            __syncthreads();
        }

        // Epilogue: O/l -> [B, N, H*HD] (concat-head layout for the O-proj GEMM)
        // C-layout: row = q = quad*4 + r (within wave's 16), col = d = l16.
#pragma unroll
        for (int r = 0; r < 4; r++) {
            float inv = 1.0f / l_sum[r];
            int tok = q0 + w * 16 + quad * 4 + r;
#pragma unroll
            for (int di = 0; di < 4; di++) {
                int d = h * 64 + di * 16 + l16;
                Oc[((size_t)(b * NN + tok)) * DD + d] = (bf16)(o_acc[di][r] * inv);
            }
        }
    }
}

// ---------------------------------------------------------------------------
extern "C" void kernel_launch(void* const* d_in, const int* in_sizes, int n_in,
                              void* d_out, int out_size, void* d_ws, size_t ws_size,
                              hipStream_t stream) {
    const float* x  = (const float*)d_in[0];
    const float* Wq = (const float*)d_in[1];
    const float* bq = (const float*)d_in[2];
    const float* Wk = (const float*)d_in[3];
    const float* bk = (const float*)d_in[4];
    const float* Wv = (const float*)d_in[5];
    const float* bv = (const float*)d_in[6];
    const float* Wo = (const float*)d_in[7];
    const float* bo = (const float*)d_in[8];

    const size_t need = (size_t)(8388608ull * 5 + 4194304ull) * sizeof(bf16);
    if (ws_size < need) return; // diagnostic: leaves d_out zeroed (absmax 3.8125)

    bf16* ws = (bf16*)d_ws;
    bf16* xb = ws;
    bf16* wt = xb + (size_t)MM * DD;
    bf16* Qw = wt + 4ull * DD * DD;       // [B*H, N, HD], pre-scaled 0.125*log2e
    bf16* Kw = Qw + (size_t)MM * DD;      // [B*H, N, HD]
    bf16* Vw = Kw + (size_t)MM * DD;      // V^T [B*H, HD, N], kv-permuted
    bf16* Aw = Vw + (size_t)MM * DD;      // attention out [B, N, D]

    convert_x<<<dim3(MM * DD / 1024), 256, 0, stream>>>(x, xb);

    transpose_w4<<<dim3(32, 32, 4), dim3(32, 8), 0, stream>>>(Wq, Wk, Wv, Wo, wt);

    gemm_bt<0><<<dim3(MM / 128, DD / 128, 3), 256, 0, stream>>>(
        xb, wt, bq, bk, bv, Qw, Kw, Vw);

    // grid (bh, 8): bh%8 -> XCD affinity; paired qi/15-qi -> every block
    // exactly 17 tile-iters (balanced residency).
    flash_attn<<<dim3(BB * HH, 8), 512, 0, stream>>>(Qw, Kw, Vw, Aw);

    gemm_bt<1><<<dim3(MM / 128, DD / 128, 1), 256, 0, stream>>>(
        Aw, wt + 3ull * DD * DD, bo, bo, bo, d_out, d_out, d_out);
}